// Round 1
// baseline (956.059 us; speedup 1.0000x reference)
//
#include <hip/hip_runtime.h>

#define H     512
#define THD   768
#define MDIM  256
#define NE    16000
#define NU    2000
#define NI    4000
#define NNZ   40000
#define KTOP  10
#define NBATCH 64
#define NEDGE 60000          // NNZ + NU*KTOP
#define GAMA  0.1f
#define P2N   12288          // NL*NB*H
#define PROMPT_N 786432      // 24*64*512

__device__ __forceinline__ float sigmoidf(float x){ return 1.0f/(1.0f+expf(-x)); }

// ---------- small dense kernels (64 rows) ----------
__global__ void k_tok(const float* __restrict__ A, const float* __restrict__ W,
                      const float* __restrict__ bias, float* __restrict__ C){
  int b=blockIdx.x, c=blockIdx.y*256+threadIdx.x;
  const float* a=A+b*THD; float s=bias[c];
  for(int k=0;k<THD;k++) s+=a[k]*W[k*H+c];
  C[b*H+c]=s;
}

__global__ void k_gm(const int* __restrict__ sysid, const float* __restrict__ tok,
                     float* __restrict__ gm){
  int b=blockIdx.x, c=blockIdx.y*256+threadIdx.x;
  int sid=sysid[b]; float s=0.f, cnt=0.f;
  for(int j=0;j<NBATCH;j++){ if(sysid[j]==sid){ s+=tok[j*H+c]; cnt+=1.f; } }
  gm[b*H+c]=s/cnt;
}

__global__ void k_filt(const float* __restrict__ gm, const float* __restrict__ W,
                       const float* __restrict__ bias, const float* __restrict__ pa,
                       float* __restrict__ filt){
  int b=blockIdx.x, c=blockIdx.y*256+threadIdx.x;
  const float* a=gm+b*H; float s=bias[c];
  for(int k=0;k<H;k++) s+=a[k]*W[k*H+c];
  float al=pa[0]; float pr = (s>=0.f)? s : al*s;
  filt[b*H+c]=pr*gm[b*H+c];
}

__global__ void k_hh(const float* __restrict__ filt, const float* __restrict__ W,
                     const float* __restrict__ bias, float* __restrict__ hh){
  int b=blockIdx.x, m=threadIdx.x;
  const float* a=filt+b*H; float s=bias[m];
  for(int k=0;k<H;k++) s+=a[k]*W[k*MDIM+m];
  hh[b*MDIM+m]=fmaxf(s,0.f);
}

__global__ void k_ue(const int* __restrict__ sysid, const float* __restrict__ ue,
                     float* __restrict__ uesel){
  int b=blockIdx.x, c=blockIdx.y*256+threadIdx.x;
  uesel[b*H+c]=ue[(size_t)sysid[b]*H+c];
}

// enhanced bias term: enh[b,k] = sum_h uesel[b,h]*mb2[h*H+k]
__global__ void k_ebias(const float* __restrict__ uesel, const float* __restrict__ mb2,
                        float* __restrict__ enh){
  int b=blockIdx.x, k=blockIdx.y*256+threadIdx.x;
  const float* u=uesel+b*H; float s=0.f;
  for(int h=0;h<H;h++) s+=u[h]*mb2[(size_t)h*H+k];
  enh[b*H+k]=s;
}

// ---------- big hypernet contraction ----------
// partials[mg][b][k] = sum_{m in group mg} sum_h hh[b,m]*ue[b,h]*W2[m,h*H+k]
#define MG   64
#define MPG  4
__global__ __launch_bounds__(256) void k_big(const float* __restrict__ hh,
        const float* __restrict__ uesel, const float* __restrict__ w2,
        float* __restrict__ partials){
  __shared__ float w_lds[64][64];
  __shared__ float a_lds[64][64];
  int mg=blockIdx.x;          // 0..63
  int kt=blockIdx.y;          // 0..7
  int k0=kt*64;
  int t=threadIdx.x;
  int kq=t&15, bo=t>>4;       // k quad, b quad
  float acc[4][4]={};
  for(int mi=0;mi<MPG;mi++){
    int m=mg*MPG+mi;
    const float* w2m = w2 + (size_t)m*(size_t)(H*H);
    for(int hc=0;hc<8;hc++){
      int h0=hc*64;
      // stage a_lds[h][b] = hh[b][m]*ue[b][h0+h]
      #pragma unroll
      for(int i=0;i<16;i++){
        int idx=t+i*256; int bb=idx&63, hl=idx>>6;
        a_lds[hl][bb]=hh[bb*MDIM+m]*uesel[bb*H+h0+hl];
      }
      // stage w_lds[h][k] = w2m[(h0+h)*H + k0+k]
      #pragma unroll
      for(int i=0;i<4;i++){
        int idx=t+i*256; int q=idx&15, hl=idx>>4;
        float4 v=*(const float4*)(w2m+(size_t)(h0+hl)*H+k0+q*4);
        *(float4*)&w_lds[hl][q*4]=v;
      }
      __syncthreads();
      #pragma unroll 8
      for(int hl=0;hl<64;hl++){
        float4 a4=*(const float4*)&a_lds[hl][bo*4];
        float4 w4=*(const float4*)&w_lds[hl][kq*4];
        acc[0][0]+=a4.x*w4.x; acc[0][1]+=a4.x*w4.y; acc[0][2]+=a4.x*w4.z; acc[0][3]+=a4.x*w4.w;
        acc[1][0]+=a4.y*w4.x; acc[1][1]+=a4.y*w4.y; acc[1][2]+=a4.y*w4.z; acc[1][3]+=a4.y*w4.w;
        acc[2][0]+=a4.z*w4.x; acc[2][1]+=a4.z*w4.y; acc[2][2]+=a4.z*w4.z; acc[2][3]+=a4.z*w4.w;
        acc[3][0]+=a4.w*w4.x; acc[3][1]+=a4.w*w4.y; acc[3][2]+=a4.w*w4.z; acc[3][3]+=a4.w*w4.w;
      }
      __syncthreads();
    }
  }
  #pragma unroll
  for(int bi=0;bi<4;bi++){
    int bb=bo*4+bi;
    float* p=partials+((size_t)mg*NBATCH+bb)*H+k0+kq*4;
    *(float4*)p=make_float4(acc[bi][0],acc[bi][1],acc[bi][2],acc[bi][3]);
  }
}

__global__ void k_enh_reduce(const float* __restrict__ partials, float* __restrict__ enh){
  int idx=blockIdx.x*256+threadIdx.x;    // 0..32767
  float s=enh[idx];
  for(int mg=0;mg<MG;mg++) s+=partials[(size_t)mg*NBATCH*H+idx];
  enh[idx]=s;
}

__global__ void k_scatter_enh(const int* __restrict__ sysid, const float* __restrict__ enh,
                              float* __restrict__ alltok){
  int b=blockIdx.x, c=blockIdx.y*256+threadIdx.x;
  alltok[(size_t)sysid[b]*H+c]=enh[b*H+c];  // duplicate sysids write identical values
}

__global__ void k_user_tok(const int* __restrict__ sysid, const float* __restrict__ gm,
                           const float* __restrict__ W, const float* __restrict__ bias,
                           const float* __restrict__ pa, float* __restrict__ usertok){
  int b=blockIdx.x, c=blockIdx.y*256+threadIdx.x;
  const float* a=gm+b*H; float s=bias[c];
  for(int k=0;k<H;k++) s+=a[k]*W[k*H+c];
  float al=pa[0]; float pr=(s>=0.f)? s : al*s;
  usertok[(size_t)sysid[b]*H+c]=pr*gm[b*H+c];
}

// ---------- tiled fp32 GEMM, BM=BN=64, BK=32, 256 thr, 4x4 per thread ----------
// EPI: 0 = (+bias if non-null), 2 = sigmoid (no bias). NT: B is [N,K] row-major.
template<int EPI, bool NT, bool AIDX>
__global__ __launch_bounds__(256) void k_gemm(const float* __restrict__ A,
        const float* __restrict__ Bm, const float* __restrict__ bias,
        const int* __restrict__ aidx, float* __restrict__ C, int M, int N, int K){
  __shared__ float As[32][68];
  __shared__ float Bs[32][68];
  int n0=blockIdx.x*64, m0=blockIdx.y*64;
  int t=threadIdx.x;
  int tn=t&15, tm=t>>4;
  float acc[4][4]={};
  for(int kt=0;kt<K;kt+=32){
    #pragma unroll
    for(int i=0;i<2;i++){
      int idx=t+i*256; int r=idx>>3, q=idx&7;
      int grow=m0+r;
      float4 v=make_float4(0.f,0.f,0.f,0.f);
      if(grow<M){
        const float* arow=A+(size_t)(AIDX? aidx[grow]:grow)*K;
        v=*(const float4*)(arow+kt+q*4);
      }
      As[q*4+0][r]=v.x; As[q*4+1][r]=v.y; As[q*4+2][r]=v.z; As[q*4+3][r]=v.w;
    }
    if(!NT){
      #pragma unroll
      for(int i=0;i<2;i++){
        int idx=t+i*256; int r=idx>>4, q=idx&15;   // N assumed multiple of 64 here
        float4 v=*(const float4*)(Bm+(size_t)(kt+r)*N+n0+q*4);
        *(float4*)&Bs[r][q*4]=v;
      }
    } else {
      #pragma unroll
      for(int i=0;i<2;i++){
        int idx=t+i*256; int r=idx>>3, q=idx&7;
        int gn=n0+r;
        float4 v=make_float4(0.f,0.f,0.f,0.f);
        if(gn<N) v=*(const float4*)(Bm+(size_t)gn*K+kt+q*4);
        Bs[q*4+0][r]=v.x; Bs[q*4+1][r]=v.y; Bs[q*4+2][r]=v.z; Bs[q*4+3][r]=v.w;
      }
    }
    __syncthreads();
    #pragma unroll 8
    for(int k=0;k<32;k++){
      float4 a4=*(const float4*)&As[k][tm*4];
      float4 b4=*(const float4*)&Bs[k][tn*4];
      acc[0][0]+=a4.x*b4.x; acc[0][1]+=a4.x*b4.y; acc[0][2]+=a4.x*b4.z; acc[0][3]+=a4.x*b4.w;
      acc[1][0]+=a4.y*b4.x; acc[1][1]+=a4.y*b4.y; acc[1][2]+=a4.y*b4.z; acc[1][3]+=a4.y*b4.w;
      acc[2][0]+=a4.z*b4.x; acc[2][1]+=a4.z*b4.y; acc[2][2]+=a4.z*b4.z; acc[2][3]+=a4.z*b4.w;
      acc[3][0]+=a4.w*b4.x; acc[3][1]+=a4.w*b4.y; acc[3][2]+=a4.w*b4.z; acc[3][3]+=a4.w*b4.w;
    }
    __syncthreads();
  }
  #pragma unroll
  for(int bi=0;bi<4;bi++){
    int row=m0+tm*4+bi; if(row>=M) continue;
    #pragma unroll
    for(int ki=0;ki<4;ki++){
      int col=n0+tn*4+ki; if(col>=N) continue;
      float v=acc[bi][ki];
      if(EPI==0){ if(bias) v+=bias[col]; }
      else { v=sigmoidf(v); }
      C[(size_t)row*N+col]=v;
    }
  }
}

__global__ __launch_bounds__(256) void k_rownorm(float* __restrict__ X){
  int r=blockIdx.x, t=threadIdx.x;
  float v1=X[(size_t)r*H+t], v2=X[(size_t)r*H+t+256];
  float ss=v1*v1+v2*v2;
  for(int o=32;o;o>>=1) ss+=__shfl_xor(ss,o);
  __shared__ float red[4];
  if((t&63)==0) red[t>>6]=ss;
  __syncthreads();
  float tot=red[0]+red[1]+red[2]+red[3];
  float nrm=fmaxf(sqrtf(tot),1e-12f);
  X[(size_t)r*H+t]=v1/nrm; X[(size_t)r*H+t+256]=v2/nrm;
}

// ---------- top-k (lax.top_k semantics: desc values, ties -> smaller index) ----------
__global__ __launch_bounds__(256) void k_topk(const float* __restrict__ sim,
        float* __restrict__ tv, int* __restrict__ ti){
  __shared__ float vals[NI];
  __shared__ float rv[256];
  __shared__ int   ri[256];
  int u=blockIdx.x, t=threadIdx.x;
  for(int i=t;i<NI;i+=256) vals[i]=sim[(size_t)u*NI+i];
  __syncthreads();
  for(int k=0;k<KTOP;k++){
    float bv=-1e30f; int bi=NI;
    for(int i=t;i<NI;i+=256){
      float v=vals[i];
      if(v>bv || (v==bv && i<bi)){ bv=v; bi=i; }
    }
    rv[t]=bv; ri[t]=bi; __syncthreads();
    for(int s=128;s>0;s>>=1){
      if(t<s){
        float ov=rv[t+s]; int oi=ri[t+s];
        if(ov>rv[t] || (ov==rv[t] && oi<ri[t])){ rv[t]=ov; ri[t]=oi; }
      }
      __syncthreads();
    }
    if(t==0){ tv[u*KTOP+k]=rv[0]; ti[u*KTOP+k]=ri[0]; vals[ri[0]]=-1e30f; }
    __syncthreads();
  }
}

// ---------- edges, CSR, normalizers ----------
__global__ void k_edges(const int* __restrict__ adj_row, const int* __restrict__ adj_col,
        const float* __restrict__ adj_val, const int* __restrict__ itemid,
        const float* __restrict__ tv, const int* __restrict__ ti,
        int* __restrict__ rows, int* __restrict__ cols, float* __restrict__ vals,
        float* __restrict__ seg_r, float* __restrict__ seg_c,
        int* __restrict__ row_cnt, int* __restrict__ col_cnt){
  int e=blockIdx.x*256+threadIdx.x; if(e>=NEDGE) return;
  int r,c; float v;
  if(e<NNZ){ r=adj_row[e]; c=adj_col[e]; v=adj_val[e]; }
  else { int x=e-NNZ; int u=x/KTOP; r=u; c=itemid[ti[x]]; v=tv[x]; }
  rows[e]=r; cols[e]=c; vals[e]=v;
  atomicAdd(&seg_r[r],v); atomicAdd(&seg_c[c],v);
  atomicAdd(&row_cnt[r],1); atomicAdd(&col_cnt[c],1);
}

__global__ __launch_bounds__(1024) void k_scan(const int* __restrict__ rc, int* __restrict__ rp,
        const int* __restrict__ cc, int* __restrict__ cp){
  const int* cnt; int* ptr; int n;
  if(blockIdx.x==0){ cnt=rc; ptr=rp; n=NU; } else { cnt=cc; ptr=cp; n=NE; }
  int t=threadIdx.x;
  int chunk=(n+1023)>>10;
  int base=t*chunk;
  int s=0;
  for(int i=0;i<chunk;i++){ int j=base+i; if(j<n) s+=cnt[j]; }
  __shared__ int buf[1024];
  buf[t]=s; __syncthreads();
  for(int off=1;off<1024;off<<=1){
    int y=(t>=off)? buf[t-off]:0;
    __syncthreads();
    buf[t]+=y;
    __syncthreads();
  }
  int run=buf[t]-s;
  for(int i=0;i<chunk;i++){ int j=base+i; if(j<n){ ptr[j]=run; run+=cnt[j]; } }
  if(t==1023) ptr[n]=buf[1023];
}

__global__ void k_fill(const int* __restrict__ rows, const int* __restrict__ cols,
        const int* __restrict__ row_ptr, const int* __restrict__ col_ptr,
        int* __restrict__ fr, int* __restrict__ fc,
        int* __restrict__ ebr, int* __restrict__ ebc){
  int e=blockIdx.x*256+threadIdx.x; if(e>=NEDGE) return;
  int r=rows[e], c=cols[e];
  ebr[row_ptr[r]+atomicAdd(&fr[r],1)]=e;
  ebc[col_ptr[c]+atomicAdd(&fc[c],1)]=e;
}

__global__ void k_vuvi(const int* __restrict__ rows, const int* __restrict__ cols,
        const float* __restrict__ vals, const float* __restrict__ seg_r,
        const float* __restrict__ seg_c, float* __restrict__ v_u, float* __restrict__ v_i){
  int e=blockIdx.x*256+threadIdx.x; if(e>=NEDGE) return;
  v_u[e]=vals[e]/seg_r[rows[e]];
  v_i[e]=vals[e]/seg_c[cols[e]];
}

// ---------- SpMM kernels (CSR, deterministic per-row loop) ----------
// out[u] = (sum_e v_u[e]*X[cols[e]]) * (1 + usertok[u])
__global__ __launch_bounds__(256) void k_spmm_u(const int* __restrict__ row_ptr,
        const int* __restrict__ ebr, const int* __restrict__ cols,
        const float* __restrict__ v_u, const float* __restrict__ X,
        const float* __restrict__ usertok, float* __restrict__ out){
  int u=blockIdx.x, t=threadIdx.x;
  float a0=0.f,a1=0.f;
  int s=row_ptr[u], e1=row_ptr[u+1];
  for(int j=s;j<e1;j++){
    int e=ebr[j]; float v=v_u[e];
    const float* xr=X+(size_t)cols[e]*H;
    a0+=v*xr[t]; a1+=v*xr[t+256];
  }
  float u0=usertok[(size_t)u*H+t], u1v=usertok[(size_t)u*H+t+256];
  out[(size_t)u*H+t]=a0+a0*u0; out[(size_t)u*H+t+256]=a1+a1*u1v;
}

// Att[i] = sum v_i*usertok[rows[e]];  i1[i] = sum v_i*alltok[rows[e]] + Att[i]*i0[i]
__global__ __launch_bounds__(256) void k_spmm_i1(const int* __restrict__ col_ptr,
        const int* __restrict__ ebc, const int* __restrict__ rows,
        const float* __restrict__ v_i, const float* __restrict__ alltok,
        const float* __restrict__ usertok, const float* __restrict__ i0,
        float* __restrict__ Att, float* __restrict__ i1){
  int i=blockIdx.x, t=threadIdx.x;
  float aA0=0.f,aA1=0.f,aU0=0.f,aU1=0.f;
  int s=col_ptr[i], e1=col_ptr[i+1];
  for(int j=s;j<e1;j++){
    int e=ebc[j]; float v=v_i[e]; int r=rows[e];
    const float* ur=usertok+(size_t)r*H;
    const float* ar=alltok+(size_t)r*H;
    aA0+=v*ur[t]; aA1+=v*ur[t+256];
    aU0+=v*ar[t]; aU1+=v*ar[t+256];
  }
  size_t o=(size_t)i*H;
  Att[o+t]=aA0; Att[o+t+256]=aA1;
  i1[o+t]=aU0+aA0*i0[o+t]; i1[o+t+256]=aU1+aA1*i0[o+t+256];
}

// i2 = sum v_i*u1[rows[e]] + Att*i1 ; item_final = (i0+i1+i2)/3 -> d_out
__global__ __launch_bounds__(256) void k_spmm_i2(const int* __restrict__ col_ptr,
        const int* __restrict__ ebc, const int* __restrict__ rows,
        const float* __restrict__ v_i, const float* __restrict__ u1,
        const float* __restrict__ Att, const float* __restrict__ i1,
        const float* __restrict__ i0, float* __restrict__ item_out){
  int i=blockIdx.x, t=threadIdx.x;
  float a0=0.f,a1=0.f;
  int s=col_ptr[i], e1=col_ptr[i+1];
  for(int j=s;j<e1;j++){
    int e=ebc[j]; float v=v_i[e];
    const float* ur=u1+(size_t)rows[e]*H;
    a0+=v*ur[t]; a1+=v*ur[t+256];
  }
  size_t o=(size_t)i*H;
  float i2a=a0+Att[o+t]*i1[o+t];
  float i2b=a1+Att[o+t+256]*i1[o+t+256];
  item_out[o+t]=(i0[o+t]+i1[o+t]+i2a)/3.0f;
  item_out[o+t+256]=(i0[o+t+256]+i1[o+t+256]+i2b)/3.0f;
}

// ---------- loss ----------
__global__ void k_inv(const int* __restrict__ itemid, int* __restrict__ inv){
  int j=blockIdx.x*256+threadIdx.x; if(j<NI) inv[itemid[j]]=j;
}
__global__ void k_dense(const int* __restrict__ adj_row, const int* __restrict__ adj_col,
        const float* __restrict__ adj_val, const int* __restrict__ inv,
        float* __restrict__ dense){
  int e=blockIdx.x*256+threadIdx.x; if(e>=NNZ) return;
  int ic=inv[adj_col[e]];
  if(ic>=0) atomicAdd(&dense[(size_t)adj_row[e]*NI+ic],adj_val[e]);
}
__global__ __launch_bounds__(256) void k_loss(const float* __restrict__ sim,
        const float* __restrict__ dense, float* __restrict__ acc){
  size_t n4=(size_t)NU*NI/4;
  float s=0.f;
  for(size_t i=(size_t)blockIdx.x*256+threadIdx.x; i<n4; i+=(size_t)gridDim.x*256){
    float4 a=((const float4*)sim)[i], d=((const float4*)dense)[i];
    float dx=a.x-d.x, dy=a.y-d.y, dz=a.z-d.z, dw=a.w-d.w;
    s+=dx*dx+dy*dy+dz*dz+dw*dw;
  }
  __shared__ float red[256];
  red[threadIdx.x]=s; __syncthreads();
  for(int o=128;o;o>>=1){ if(threadIdx.x<o) red[threadIdx.x]+=red[threadIdx.x+o]; __syncthreads(); }
  if(threadIdx.x==0) atomicAdd(acc,red[0]);
}
__global__ void k_loss_write(const float* __restrict__ acc, float* __restrict__ out){
  out[0]=GAMA*(acc[0]/(float)((size_t)NU*NI));
}

// ---------- prompt head ----------
__global__ void k_sysfin(const int* __restrict__ sysid, const float* __restrict__ u0,
        const float* __restrict__ u1, const float* __restrict__ u2, float* __restrict__ sysf){
  int b=blockIdx.x, c=blockIdx.y*256+threadIdx.x;
  size_t o=(size_t)sysid[b]*H+c;
  sysf[b*H+c]=(u0[o]+u1[o]+u2[o])/3.0f;
}
__global__ void k_q(const float* __restrict__ sysf, const float* __restrict__ W,
        const float* __restrict__ bias, float* __restrict__ q){
  int b=blockIdx.x, m=threadIdx.x;
  const float* a=sysf+b*H; float s=bias[m];
  for(int k=0;k<H;k++) s+=a[k]*W[k*MDIM+m];
  q[b*MDIM+m]=fmaxf(s,0.f);
}
__global__ void k_p1(const float* __restrict__ q, const float* __restrict__ W,
        const float* __restrict__ bias, const float* __restrict__ sysf, float* __restrict__ p1){
  int b=blockIdx.x, c=blockIdx.y*256+threadIdx.x;
  const float* a=q+b*MDIM; float s=bias[c];
  for(int k=0;k<MDIM;k++) s+=a[k]*W[k*H+c];
  p1[b*H+c]=s+sysf[b*H+c];
}
__global__ void k_perm(const float* __restrict__ p2, float* __restrict__ out){
  int idx=blockIdx.x*256+threadIdx.x;       // 0..786431
  int x=idx&511;
  int b=(idx>>9)&63;
  int c=idx>>15;                            // 0..23
  out[idx]=p2[(size_t)b*P2N+c*512+x];
}

// ---------- host ----------
extern "C" void kernel_launch(void* const* d_in, const int* in_sizes, int n_in,
                              void* d_out, int out_size, void* d_ws, size_t ws_size,
                              hipStream_t stream){
  const int*   sysid   =(const int*)  d_in[0];
  const int*   adj_row =(const int*)  d_in[1];
  const int*   adj_col =(const int*)  d_in[2];
  const int*   itemid  =(const int*)  d_in[3];
  const float* tok_emb =(const float*)d_in[4];
  const float* adj_val =(const float*)d_in[5];
  const float* node_emb=(const float*)d_in[6];
  const float* user_emb=(const float*)d_in[7];
  const float* tp_w    =(const float*)d_in[8];
  const float* tp_b    =(const float*)d_in[9];
  const float* trans_w =(const float*)d_in[10];
  const float* trans_b =(const float*)d_in[11];
  const float* trt_w   =(const float*)d_in[12];
  const float* trt_b   =(const float*)d_in[13];
  const float* mw1     =(const float*)d_in[14];
  const float* mb1     =(const float*)d_in[15];
  const float* mw2     =(const float*)d_in[16];
  const float* mb2     =(const float*)d_in[17];
  const float* sw1     =(const float*)d_in[18];
  const float* sw2     =(const float*)d_in[19];
  const float* p1w1    =(const float*)d_in[20];
  const float* p1b1    =(const float*)d_in[21];
  const float* p1w2    =(const float*)d_in[22];
  const float* p1b2    =(const float*)d_in[23];
  const float* p2w     =(const float*)d_in[24];
  const float* p2b     =(const float*)d_in[25];
  const float* pa      =(const float*)d_in[26];

  float* out_prompt=(float*)d_out;
  float* out_item  =out_prompt+PROMPT_N;
  float* out_loss  =out_item+(size_t)NE*H;

  // workspace arena (~101 MB total)
  char* ws=(char*)d_ws; size_t off=0;
  auto A=[&](size_t bytes)->char*{ char* p=ws+off; off+=(bytes+255)&~(size_t)255; return p; };
  float* tok     =(float*)A((size_t)NBATCH*H*4);
  float* gm      =(float*)A((size_t)NBATCH*H*4);
  float* filt    =(float*)A((size_t)NBATCH*H*4);
  float* hh      =(float*)A((size_t)NBATCH*MDIM*4);
  float* uesel   =(float*)A((size_t)NBATCH*H*4);
  float* enh     =(float*)A((size_t)NBATCH*H*4);
  float* partials=(float*)A((size_t)MG*NBATCH*H*4);      // 8 MB; reused as i_rep
  float* irep    =partials;                              // 4000*512 floats fits
  float* alltok  =(float*)A((size_t)NU*H*4);
  float* usertok =(float*)A((size_t)NU*H*4);
  float* urep    =(float*)A((size_t)NU*H*4);
  float* u1      =(float*)A((size_t)NU*H*4);
  float* u2      =(float*)A((size_t)NU*H*4);
  float* big     =(float*)A((size_t)16384000*4);         // 64 MB region
  float* sim     =big;                                   // 8,000,000 f
  float* dense   =big+8000000;                           // 8,000,000 f
  float* Att     =big;                                   // after loss: 8,192,000 f
  float* i1      =big+8192000;                           // after loss: 8,192,000 f
  float* tv      =(float*)A((size_t)NU*KTOP*4);
  int*   ti      =(int*)  A((size_t)NU*KTOP*4);
  int*   rowsA   =(int*)  A((size_t)NEDGE*4);
  int*   colsA   =(int*)  A((size_t)NEDGE*4);
  float* valsA   =(float*)A((size_t)NEDGE*4);
  float* v_u     =(float*)A((size_t)NEDGE*4);
  float* v_i     =(float*)A((size_t)NEDGE*4);
  int*   ebr     =(int*)  A((size_t)NEDGE*4);
  int*   ebc     =(int*)  A((size_t)NEDGE*4);
  int*   row_ptr =(int*)  A((size_t)(NU+1)*4);
  int*   col_ptr =(int*)  A((size_t)(NE+1)*4);
  // contiguous zero block
  size_t zb_bytes=(size_t)(NU+NE)*4*3+256;
  char*  zb      =A(zb_bytes);
  float* seg_r   =(float*)zb;
  float* seg_c   =seg_r+NU;
  int*   row_cnt =(int*)(seg_c+NE);
  int*   col_cnt =row_cnt+NU;
  int*   fr      =col_cnt+NE;
  int*   fc      =fr+NU;
  float* loss_acc=(float*)(fc+NE);
  int*   inv     =(int*)  A((size_t)NE*4);
  float* sysf    =(float*)A((size_t)NBATCH*H*4);
  float* qbuf    =(float*)A((size_t)NBATCH*MDIM*4);
  float* p1buf   =(float*)A((size_t)NBATCH*H*4);
  float* p2buf   =(float*)A((size_t)NBATCH*P2N*4);
  (void)ws_size; (void)n_in; (void)in_sizes; (void)out_size;

  dim3 g642(NBATCH,2);

  // dense front-end
  k_tok  <<<g642,256,0,stream>>>(tok_emb,tp_w,tp_b,tok);
  k_gm   <<<g642,256,0,stream>>>(sysid,tok,gm);
  k_filt <<<g642,256,0,stream>>>(gm,trans_w,trans_b,pa,filt);
  k_hh   <<<NBATCH,256,0,stream>>>(filt,mw1,mb1,hh);
  k_ue   <<<g642,256,0,stream>>>(sysid,user_emb,uesel);
  k_ebias<<<g642,256,0,stream>>>(uesel,mb2,enh);
  k_big  <<<dim3(MG,8),256,0,stream>>>(hh,uesel,mw2,partials);
  k_enh_reduce<<<128,256,0,stream>>>(partials,enh);

  hipMemcpyAsync(alltok,user_emb,(size_t)NU*H*4,hipMemcpyDeviceToDevice,stream);
  k_scatter_enh<<<g642,256,0,stream>>>(sysid,enh,alltok);
  hipMemsetAsync(usertok,0,(size_t)NU*H*4,stream);
  k_user_tok<<<g642,256,0,stream>>>(sysid,gm,trt_w,trt_b,pa,usertok);

  // similarity
  k_gemm<0,false,false><<<dim3(8,32),256,0,stream>>>(alltok,sw1,nullptr,nullptr,urep,NU,H,H);
  k_gemm<0,false,true> <<<dim3(8,63),256,0,stream>>>(node_emb,sw2,nullptr,itemid,irep,NI,H,H);
  k_rownorm<<<NU,256,0,stream>>>(urep);
  k_rownorm<<<NI,256,0,stream>>>(irep);
  k_gemm<2,true,false><<<dim3(63,32),256,0,stream>>>(urep,irep,nullptr,nullptr,sim,NU,NI,H);
  k_topk<<<NU,256,0,stream>>>(sim,tv,ti);

  // edges + CSR
  hipMemsetAsync(zb,0,zb_bytes,stream);
  k_edges<<<(NEDGE+255)/256,256,0,stream>>>(adj_row,adj_col,adj_val,itemid,tv,ti,
                                            rowsA,colsA,valsA,seg_r,seg_c,row_cnt,col_cnt);
  k_scan<<<2,1024,0,stream>>>(row_cnt,row_ptr,col_cnt,col_ptr);
  k_fill<<<(NEDGE+255)/256,256,0,stream>>>(rowsA,colsA,row_ptr,col_ptr,fr,fc,ebr,ebc);
  k_vuvi<<<(NEDGE+255)/256,256,0,stream>>>(rowsA,colsA,valsA,seg_r,seg_c,v_u,v_i);

  // loss (consumes sim+dense, must finish before Att/i1 reuse the region)
  hipMemsetAsync(inv,0xFF,(size_t)NE*4,stream);
  k_inv<<<(NI+255)/256,256,0,stream>>>(itemid,inv);
  hipMemsetAsync(dense,0,(size_t)8000000*4,stream);
  k_dense<<<(NNZ+255)/256,256,0,stream>>>(adj_row,adj_col,adj_val,inv,dense);
  k_loss<<<2048,256,0,stream>>>(sim,dense,loss_acc);
  k_loss_write<<<1,1,0,stream>>>(loss_acc,out_loss);

  // propagation
  k_spmm_u <<<NU,256,0,stream>>>(row_ptr,ebr,colsA,v_u,node_emb,usertok,u1);
  k_spmm_i1<<<NE,256,0,stream>>>(col_ptr,ebc,rowsA,v_i,alltok,usertok,node_emb,Att,i1);
  k_spmm_u <<<NU,256,0,stream>>>(row_ptr,ebr,colsA,v_u,i1,usertok,u2);
  k_spmm_i2<<<NE,256,0,stream>>>(col_ptr,ebc,rowsA,v_i,u1,Att,i1,node_emb,out_item);

  // prompt head
  k_sysfin<<<g642,256,0,stream>>>(sysid,alltok,u1,u2,sysf);
  k_q  <<<NBATCH,256,0,stream>>>(sysf,p1w1,p1b1,qbuf);
  k_p1 <<<g642,256,0,stream>>>(qbuf,p1w2,p1b2,sysf,p1buf);
  k_gemm<0,false,false><<<dim3(192,1),256,0,stream>>>(p1buf,p2w,p2b,nullptr,p2buf,NBATCH,P2N,H);
  k_perm<<<PROMPT_N/256,256,0,stream>>>(p2buf,out_prompt);
}

// Round 2
// 924.870 us; speedup vs baseline: 1.0337x; 1.0337x over previous
//
#include <hip/hip_runtime.h>

#define H     512
#define THD   768
#define MDIM  256
#define NE    16000
#define NU    2000
#define NI    4000
#define NNZ   40000
#define KTOP  10
#define NBATCH 64
#define NEDGE 60000          // NNZ + NU*KTOP
#define GAMA  0.1f
#define P2N   12288          // NL*NB*H
#define PROMPT_N 786432      // 24*64*512

__device__ __forceinline__ float sigmoidf(float x){ return 1.0f/(1.0f+expf(-x)); }

// ---------- small dense kernels (64 rows) ----------
__global__ void k_tok(const float* __restrict__ A, const float* __restrict__ W,
                      const float* __restrict__ bias, float* __restrict__ C){
  int b=blockIdx.x, c=blockIdx.y*256+threadIdx.x;
  const float* a=A+b*THD; float s=bias[c];
  for(int k=0;k<THD;k++) s+=a[k]*W[k*H+c];
  C[b*H+c]=s;
}

__global__ void k_gm(const int* __restrict__ sysid, const float* __restrict__ tok,
                     float* __restrict__ gm){
  int b=blockIdx.x, c=blockIdx.y*256+threadIdx.x;
  int sid=sysid[b]; float s=0.f, cnt=0.f;
  for(int j=0;j<NBATCH;j++){ if(sysid[j]==sid){ s+=tok[j*H+c]; cnt+=1.f; } }
  gm[b*H+c]=s/cnt;
}

__global__ void k_filt(const float* __restrict__ gm, const float* __restrict__ W,
                       const float* __restrict__ bias, const float* __restrict__ pa,
                       float* __restrict__ filt){
  int b=blockIdx.x, c=blockIdx.y*256+threadIdx.x;
  const float* a=gm+b*H; float s=bias[c];
  for(int k=0;k<H;k++) s+=a[k]*W[k*H+c];
  float al=pa[0]; float pr = (s>=0.f)? s : al*s;
  filt[b*H+c]=pr*gm[b*H+c];
}

__global__ void k_hh(const float* __restrict__ filt, const float* __restrict__ W,
                     const float* __restrict__ bias, float* __restrict__ hh){
  int b=blockIdx.x, m=threadIdx.x;
  const float* a=filt+b*H; float s=bias[m];
  for(int k=0;k<H;k++) s+=a[k]*W[k*MDIM+m];
  hh[b*MDIM+m]=fmaxf(s,0.f);
}

__global__ void k_ue(const int* __restrict__ sysid, const float* __restrict__ ue,
                     float* __restrict__ uesel){
  int b=blockIdx.x, c=blockIdx.y*256+threadIdx.x;
  uesel[b*H+c]=ue[(size_t)sysid[b]*H+c];
}

// enhanced bias term: enh[b,k] = sum_h uesel[b,h]*mb2[h*H+k]
__global__ void k_ebias(const float* __restrict__ uesel, const float* __restrict__ mb2,
                        float* __restrict__ enh){
  int b=blockIdx.x, k=blockIdx.y*256+threadIdx.x;
  const float* u=uesel+b*H; float s=0.f;
  for(int h=0;h<H;h++) s+=u[h]*mb2[(size_t)h*H+k];
  enh[b*H+k]=s;
}

// ---------- big hypernet contraction ----------
// partials[m][b][k] = sum_h hh[b,m]*ue[b,h]*W2[m,h*H+k]
// grid (256 m, 8 kt) = 2048 blocks -> 8 blocks/CU (was 512 -> occupancy 22%)
__global__ __launch_bounds__(256) void k_big(const float* __restrict__ hh,
        const float* __restrict__ uesel, const float* __restrict__ w2,
        float* __restrict__ partials){
  __shared__ float w_lds[64][64];
  __shared__ float a_lds[64][64];
  int m=blockIdx.x;           // 0..255
  int kt=blockIdx.y;          // 0..7
  int k0=kt*64;
  int t=threadIdx.x;
  int kq=t&15, bo=t>>4;       // k quad, b quad
  float acc[4][4]={};
  const float* w2m = w2 + (size_t)m*(size_t)(H*H);
  for(int hc=0;hc<8;hc++){
    int h0=hc*64;
    // stage a_lds[h][b] = hh[b][m]*ue[b][h0+h]  (once per hc; strided global
    // reads hit L1/L2 — uesel is 128 KB resident)
    #pragma unroll
    for(int i=0;i<16;i++){
      int idx=t+i*256; int bb=idx&63, hl=idx>>6;
      a_lds[hl][bb]=hh[bb*MDIM+m]*uesel[bb*H+h0+hl];
    }
    // stage w_lds[h][k] = w2m[(h0+h)*H + k0+k]
    #pragma unroll
    for(int i=0;i<4;i++){
      int idx=t+i*256; int q=idx&15, hl=idx>>4;
      float4 v=*(const float4*)(w2m+(size_t)(h0+hl)*H+k0+q*4);
      *(float4*)&w_lds[hl][q*4]=v;
    }
    __syncthreads();
    #pragma unroll 8
    for(int hl=0;hl<64;hl++){
      float4 a4=*(const float4*)&a_lds[hl][bo*4];
      float4 w4=*(const float4*)&w_lds[hl][kq*4];
      acc[0][0]+=a4.x*w4.x; acc[0][1]+=a4.x*w4.y; acc[0][2]+=a4.x*w4.z; acc[0][3]+=a4.x*w4.w;
      acc[1][0]+=a4.y*w4.x; acc[1][1]+=a4.y*w4.y; acc[1][2]+=a4.y*w4.z; acc[1][3]+=a4.y*w4.w;
      acc[2][0]+=a4.z*w4.x; acc[2][1]+=a4.z*w4.y; acc[2][2]+=a4.z*w4.z; acc[2][3]+=a4.z*w4.w;
      acc[3][0]+=a4.w*w4.x; acc[3][1]+=a4.w*w4.y; acc[3][2]+=a4.w*w4.z; acc[3][3]+=a4.w*w4.w;
    }
    __syncthreads();
  }
  #pragma unroll
  for(int bi=0;bi<4;bi++){
    int bb=bo*4+bi;
    float* p=partials+((size_t)m*NBATCH+bb)*H+k0+kq*4;
    *(float4*)p=make_float4(acc[bi][0],acc[bi][1],acc[bi][2],acc[bi][3]);
  }
}

// two-stage reduction over the 256 m-partials (stage1: 2048 blocks, coalesced)
__global__ void k_red1(const float* __restrict__ partials, float* __restrict__ partial2){
  int idx=blockIdx.x*256+threadIdx.x;      // 0..524287
  int g=idx>>15, col=idx&32767;            // g: 16 groups of 16 m's
  const float* p=partials+(size_t)g*16*32768+col;
  float s=0.f;
  #pragma unroll
  for(int m=0;m<16;m++) s+=p[(size_t)m*32768];
  partial2[idx]=s;
}
__global__ void k_red2(const float* __restrict__ partial2, float* __restrict__ enh){
  int idx=blockIdx.x*256+threadIdx.x;      // 0..32767
  float s=enh[idx];
  #pragma unroll
  for(int g=0;g<16;g++) s+=partial2[(size_t)g*32768+idx];
  enh[idx]=s;
}

__global__ void k_scatter_enh(const int* __restrict__ sysid, const float* __restrict__ enh,
                              float* __restrict__ alltok){
  int b=blockIdx.x, c=blockIdx.y*256+threadIdx.x;
  alltok[(size_t)sysid[b]*H+c]=enh[b*H+c];  // duplicate sysids write identical values
}

__global__ void k_user_tok(const int* __restrict__ sysid, const float* __restrict__ gm,
                           const float* __restrict__ W, const float* __restrict__ bias,
                           const float* __restrict__ pa, float* __restrict__ usertok){
  int b=blockIdx.x, c=blockIdx.y*256+threadIdx.x;
  const float* a=gm+b*H; float s=bias[c];
  for(int k=0;k<H;k++) s+=a[k]*W[k*H+c];
  float al=pa[0]; float pr=(s>=0.f)? s : al*s;
  usertok[(size_t)sysid[b]*H+c]=pr*gm[b*H+c];
}

// ---------- tiled fp32 GEMM, BM=BN=64, BK=32, 256 thr, 4x4 per thread ----------
// EPI: 0 = (+bias if non-null), 2 = sigmoid (no bias). NT: B is [N,K] row-major.
template<int EPI, bool NT, bool AIDX>
__global__ __launch_bounds__(256) void k_gemm(const float* __restrict__ A,
        const float* __restrict__ Bm, const float* __restrict__ bias,
        const int* __restrict__ aidx, float* __restrict__ C, int M, int N, int K){
  __shared__ float As[32][68];
  __shared__ float Bs[32][68];
  int n0=blockIdx.x*64, m0=blockIdx.y*64;
  int t=threadIdx.x;
  int tn=t&15, tm=t>>4;
  float acc[4][4]={};
  for(int kt=0;kt<K;kt+=32){
    #pragma unroll
    for(int i=0;i<2;i++){
      int idx=t+i*256; int r=idx>>3, q=idx&7;
      int grow=m0+r;
      float4 v=make_float4(0.f,0.f,0.f,0.f);
      if(grow<M){
        const float* arow=A+(size_t)(AIDX? aidx[grow]:grow)*K;
        v=*(const float4*)(arow+kt+q*4);
      }
      As[q*4+0][r]=v.x; As[q*4+1][r]=v.y; As[q*4+2][r]=v.z; As[q*4+3][r]=v.w;
    }
    if(!NT){
      #pragma unroll
      for(int i=0;i<2;i++){
        int idx=t+i*256; int r=idx>>4, q=idx&15;   // N assumed multiple of 64 here
        float4 v=*(const float4*)(Bm+(size_t)(kt+r)*N+n0+q*4);
        *(float4*)&Bs[r][q*4]=v;
      }
    } else {
      #pragma unroll
      for(int i=0;i<2;i++){
        int idx=t+i*256; int r=idx>>3, q=idx&7;
        int gn=n0+r;
        float4 v=make_float4(0.f,0.f,0.f,0.f);
        if(gn<N) v=*(const float4*)(Bm+(size_t)gn*K+kt+q*4);
        Bs[q*4+0][r]=v.x; Bs[q*4+1][r]=v.y; Bs[q*4+2][r]=v.z; Bs[q*4+3][r]=v.w;
      }
    }
    __syncthreads();
    #pragma unroll 8
    for(int k=0;k<32;k++){
      float4 a4=*(const float4*)&As[k][tm*4];
      float4 b4=*(const float4*)&Bs[k][tn*4];
      acc[0][0]+=a4.x*b4.x; acc[0][1]+=a4.x*b4.y; acc[0][2]+=a4.x*b4.z; acc[0][3]+=a4.x*b4.w;
      acc[1][0]+=a4.y*b4.x; acc[1][1]+=a4.y*b4.y; acc[1][2]+=a4.y*b4.z; acc[1][3]+=a4.y*b4.w;
      acc[2][0]+=a4.z*b4.x; acc[2][1]+=a4.z*b4.y; acc[2][2]+=a4.z*b4.z; acc[2][3]+=a4.z*b4.w;
      acc[3][0]+=a4.w*b4.x; acc[3][1]+=a4.w*b4.y; acc[3][2]+=a4.w*b4.z; acc[3][3]+=a4.w*b4.w;
    }
    __syncthreads();
  }
  #pragma unroll
  for(int bi=0;bi<4;bi++){
    int row=m0+tm*4+bi; if(row>=M) continue;
    #pragma unroll
    for(int ki=0;ki<4;ki++){
      int col=n0+tn*4+ki; if(col>=N) continue;
      float v=acc[bi][ki];
      if(EPI==0){ if(bias) v+=bias[col]; }
      else { v=sigmoidf(v); }
      C[(size_t)row*N+col]=v;
    }
  }
}

__global__ __launch_bounds__(256) void k_rownorm(float* __restrict__ X){
  int r=blockIdx.x, t=threadIdx.x;
  float v1=X[(size_t)r*H+t], v2=X[(size_t)r*H+t+256];
  float ss=v1*v1+v2*v2;
  for(int o=32;o;o>>=1) ss+=__shfl_xor(ss,o);
  __shared__ float red[4];
  if((t&63)==0) red[t>>6]=ss;
  __syncthreads();
  float tot=red[0]+red[1]+red[2]+red[3];
  float nrm=fmaxf(sqrtf(tot),1e-12f);
  X[(size_t)r*H+t]=v1/nrm; X[(size_t)r*H+t+256]=v2/nrm;
}

// ---------- top-k (lax.top_k semantics: desc values, ties -> smaller index) ----------
__global__ __launch_bounds__(256) void k_topk(const float* __restrict__ sim,
        float* __restrict__ tv, int* __restrict__ ti){
  __shared__ float vals[NI];
  __shared__ float rv[256];
  __shared__ int   ri[256];
  int u=blockIdx.x, t=threadIdx.x;
  for(int i=t;i<NI;i+=256) vals[i]=sim[(size_t)u*NI+i];
  __syncthreads();
  for(int k=0;k<KTOP;k++){
    float bv=-1e30f; int bi=NI;
    for(int i=t;i<NI;i+=256){
      float v=vals[i];
      if(v>bv || (v==bv && i<bi)){ bv=v; bi=i; }
    }
    rv[t]=bv; ri[t]=bi; __syncthreads();
    for(int s=128;s>0;s>>=1){
      if(t<s){
        float ov=rv[t+s]; int oi=ri[t+s];
        if(ov>rv[t] || (ov==rv[t] && oi<ri[t])){ rv[t]=ov; ri[t]=oi; }
      }
      __syncthreads();
    }
    if(t==0){ tv[u*KTOP+k]=rv[0]; ti[u*KTOP+k]=ri[0]; vals[ri[0]]=-1e30f; }
    __syncthreads();
  }
}

// ---------- edges, CSR, normalizers ----------
__global__ void k_edges(const int* __restrict__ adj_row, const int* __restrict__ adj_col,
        const float* __restrict__ adj_val, const int* __restrict__ itemid,
        const float* __restrict__ tv, const int* __restrict__ ti,
        int* __restrict__ rows, int* __restrict__ cols, float* __restrict__ vals,
        float* __restrict__ seg_r, float* __restrict__ seg_c,
        int* __restrict__ row_cnt, int* __restrict__ col_cnt){
  int e=blockIdx.x*256+threadIdx.x; if(e>=NEDGE) return;
  int r,c; float v;
  if(e<NNZ){ r=adj_row[e]; c=adj_col[e]; v=adj_val[e]; }
  else { int x=e-NNZ; int u=x/KTOP; r=u; c=itemid[ti[x]]; v=tv[x]; }
  rows[e]=r; cols[e]=c; vals[e]=v;
  atomicAdd(&seg_r[r],v); atomicAdd(&seg_c[c],v);
  atomicAdd(&row_cnt[r],1); atomicAdd(&col_cnt[c],1);
}

__global__ __launch_bounds__(1024) void k_scan(const int* __restrict__ rc, int* __restrict__ rp,
        const int* __restrict__ cc, int* __restrict__ cp){
  const int* cnt; int* ptr; int n;
  if(blockIdx.x==0){ cnt=rc; ptr=rp; n=NU; } else { cnt=cc; ptr=cp; n=NE; }
  int t=threadIdx.x;
  int chunk=(n+1023)>>10;
  int base=t*chunk;
  int s=0;
  for(int i=0;i<chunk;i++){ int j=base+i; if(j<n) s+=cnt[j]; }
  __shared__ int buf[1024];
  buf[t]=s; __syncthreads();
  for(int off=1;off<1024;off<<=1){
    int y=(t>=off)? buf[t-off]:0;
    __syncthreads();
    buf[t]+=y;
    __syncthreads();
  }
  int run=buf[t]-s;
  for(int i=0;i<chunk;i++){ int j=base+i; if(j<n){ ptr[j]=run; run+=cnt[j]; } }
  if(t==1023) ptr[n]=buf[1023];
}

__global__ void k_fill(const int* __restrict__ rows, const int* __restrict__ cols,
        const int* __restrict__ row_ptr, const int* __restrict__ col_ptr,
        int* __restrict__ fr, int* __restrict__ fc,
        int* __restrict__ ebr, int* __restrict__ ebc){
  int e=blockIdx.x*256+threadIdx.x; if(e>=NEDGE) return;
  int r=rows[e], c=cols[e];
  ebr[row_ptr[r]+atomicAdd(&fr[r],1)]=e;
  ebc[col_ptr[c]+atomicAdd(&fc[c],1)]=e;
}

__global__ void k_vuvi(const int* __restrict__ rows, const int* __restrict__ cols,
        const float* __restrict__ vals, const float* __restrict__ seg_r,
        const float* __restrict__ seg_c, float* __restrict__ v_u, float* __restrict__ v_i){
  int e=blockIdx.x*256+threadIdx.x; if(e>=NEDGE) return;
  v_u[e]=vals[e]/seg_r[rows[e]];
  v_i[e]=vals[e]/seg_c[cols[e]];
}

// ---------- SpMM kernels (CSR, deterministic per-row loop) ----------
__global__ __launch_bounds__(256) void k_spmm_u(const int* __restrict__ row_ptr,
        const int* __restrict__ ebr, const int* __restrict__ cols,
        const float* __restrict__ v_u, const float* __restrict__ X,
        const float* __restrict__ usertok, float* __restrict__ out){
  int u=blockIdx.x, t=threadIdx.x;
  float a0=0.f,a1=0.f;
  int s=row_ptr[u], e1=row_ptr[u+1];
  for(int j=s;j<e1;j++){
    int e=ebr[j]; float v=v_u[e];
    const float* xr=X+(size_t)cols[e]*H;
    a0+=v*xr[t]; a1+=v*xr[t+256];
  }
  float u0=usertok[(size_t)u*H+t], u1v=usertok[(size_t)u*H+t+256];
  out[(size_t)u*H+t]=a0+a0*u0; out[(size_t)u*H+t+256]=a1+a1*u1v;
}

__global__ __launch_bounds__(256) void k_spmm_i1(const int* __restrict__ col_ptr,
        const int* __restrict__ ebc, const int* __restrict__ rows,
        const float* __restrict__ v_i, const float* __restrict__ alltok,
        const float* __restrict__ usertok, const float* __restrict__ i0,
        float* __restrict__ Att, float* __restrict__ i1){
  int i=blockIdx.x, t=threadIdx.x;
  float aA0=0.f,aA1=0.f,aU0=0.f,aU1=0.f;
  int s=col_ptr[i], e1=col_ptr[i+1];
  for(int j=s;j<e1;j++){
    int e=ebc[j]; float v=v_i[e]; int r=rows[e];
    const float* ur=usertok+(size_t)r*H;
    const float* ar=alltok+(size_t)r*H;
    aA0+=v*ur[t]; aA1+=v*ur[t+256];
    aU0+=v*ar[t]; aU1+=v*ar[t+256];
  }
  size_t o=(size_t)i*H;
  Att[o+t]=aA0; Att[o+t+256]=aA1;
  i1[o+t]=aU0+aA0*i0[o+t]; i1[o+t+256]=aU1+aA1*i0[o+t+256];
}

__global__ __launch_bounds__(256) void k_spmm_i2(const int* __restrict__ col_ptr,
        const int* __restrict__ ebc, const int* __restrict__ rows,
        const float* __restrict__ v_i, const float* __restrict__ u1,
        const float* __restrict__ Att, const float* __restrict__ i1,
        const float* __restrict__ i0, float* __restrict__ item_out){
  int i=blockIdx.x, t=threadIdx.x;
  float a0=0.f,a1=0.f;
  int s=col_ptr[i], e1=col_ptr[i+1];
  for(int j=s;j<e1;j++){
    int e=ebc[j]; float v=v_i[e];
    const float* ur=u1+(size_t)rows[e]*H;
    a0+=v*ur[t]; a1+=v*ur[t+256];
  }
  size_t o=(size_t)i*H;
  float i2a=a0+Att[o+t]*i1[o+t];
  float i2b=a1+Att[o+t+256]*i1[o+t+256];
  item_out[o+t]=(i0[o+t]+i1[o+t]+i2a)/3.0f;
  item_out[o+t+256]=(i0[o+t+256]+i1[o+t+256]+i2b)/3.0f;
}

// ---------- loss ----------
__global__ void k_inv(const int* __restrict__ itemid, int* __restrict__ inv){
  int j=blockIdx.x*256+threadIdx.x; if(j<NI) inv[itemid[j]]=j;
}
__global__ void k_dense(const int* __restrict__ adj_row, const int* __restrict__ adj_col,
        const float* __restrict__ adj_val, const int* __restrict__ inv,
        float* __restrict__ dense){
  int e=blockIdx.x*256+threadIdx.x; if(e>=NNZ) return;
  int ic=inv[adj_col[e]];
  if(ic>=0) atomicAdd(&dense[(size_t)adj_row[e]*NI+ic],adj_val[e]);
}
__global__ __launch_bounds__(256) void k_loss(const float* __restrict__ sim,
        const float* __restrict__ dense, float* __restrict__ acc){
  size_t n4=(size_t)NU*NI/4;
  float s=0.f;
  for(size_t i=(size_t)blockIdx.x*256+threadIdx.x; i<n4; i+=(size_t)gridDim.x*256){
    float4 a=((const float4*)sim)[i], d=((const float4*)dense)[i];
    float dx=a.x-d.x, dy=a.y-d.y, dz=a.z-d.z, dw=a.w-d.w;
    s+=dx*dx+dy*dy+dz*dz+dw*dw;
  }
  __shared__ float red[256];
  red[threadIdx.x]=s; __syncthreads();
  for(int o=128;o;o>>=1){ if(threadIdx.x<o) red[threadIdx.x]+=red[threadIdx.x+o]; __syncthreads(); }
  if(threadIdx.x==0) atomicAdd(acc,red[0]);
}
__global__ void k_loss_write(const float* __restrict__ acc, float* __restrict__ out){
  out[0]=GAMA*(acc[0]/(float)((size_t)NU*NI));
}

// ---------- prompt head ----------
__global__ void k_sysfin(const int* __restrict__ sysid, const float* __restrict__ u0,
        const float* __restrict__ u1, const float* __restrict__ u2, float* __restrict__ sysf){
  int b=blockIdx.x, c=blockIdx.y*256+threadIdx.x;
  size_t o=(size_t)sysid[b]*H+c;
  sysf[b*H+c]=(u0[o]+u1[o]+u2[o])/3.0f;
}
__global__ void k_q(const float* __restrict__ sysf, const float* __restrict__ W,
        const float* __restrict__ bias, float* __restrict__ q){
  int b=blockIdx.x, m=threadIdx.x;
  const float* a=sysf+b*H; float s=bias[m];
  for(int k=0;k<H;k++) s+=a[k]*W[k*MDIM+m];
  q[b*MDIM+m]=fmaxf(s,0.f);
}
__global__ void k_p1(const float* __restrict__ q, const float* __restrict__ W,
        const float* __restrict__ bias, const float* __restrict__ sysf, float* __restrict__ p1){
  int b=blockIdx.x, c=blockIdx.y*256+threadIdx.x;
  const float* a=q+b*MDIM; float s=bias[c];
  for(int k=0;k<MDIM;k++) s+=a[k]*W[k*H+c];
  p1[b*H+c]=s+sysf[b*H+c];
}
__global__ void k_perm(const float* __restrict__ p2, float* __restrict__ out){
  int idx=blockIdx.x*256+threadIdx.x;       // 0..786431
  int x=idx&511;
  int b=(idx>>9)&63;
  int c=idx>>15;                            // 0..23
  out[idx]=p2[(size_t)b*P2N+c*512+x];
}

// ---------- host ----------
extern "C" void kernel_launch(void* const* d_in, const int* in_sizes, int n_in,
                              void* d_out, int out_size, void* d_ws, size_t ws_size,
                              hipStream_t stream){
  const int*   sysid   =(const int*)  d_in[0];
  const int*   adj_row =(const int*)  d_in[1];
  const int*   adj_col =(const int*)  d_in[2];
  const int*   itemid  =(const int*)  d_in[3];
  const float* tok_emb =(const float*)d_in[4];
  const float* adj_val =(const float*)d_in[5];
  const float* node_emb=(const float*)d_in[6];
  const float* user_emb=(const float*)d_in[7];
  const float* tp_w    =(const float*)d_in[8];
  const float* tp_b    =(const float*)d_in[9];
  const float* trans_w =(const float*)d_in[10];
  const float* trans_b =(const float*)d_in[11];
  const float* trt_w   =(const float*)d_in[12];
  const float* trt_b   =(const float*)d_in[13];
  const float* mw1     =(const float*)d_in[14];
  const float* mb1     =(const float*)d_in[15];
  const float* mw2     =(const float*)d_in[16];
  const float* mb2     =(const float*)d_in[17];
  const float* sw1     =(const float*)d_in[18];
  const float* sw2     =(const float*)d_in[19];
  const float* p1w1    =(const float*)d_in[20];
  const float* p1b1    =(const float*)d_in[21];
  const float* p1w2    =(const float*)d_in[22];
  const float* p1b2    =(const float*)d_in[23];
  const float* p2w     =(const float*)d_in[24];
  const float* p2b     =(const float*)d_in[25];
  const float* pa      =(const float*)d_in[26];

  float* out_prompt=(float*)d_out;
  float* out_item  =out_prompt+PROMPT_N;
  float* out_loss  =out_item+(size_t)NE*H;

  // workspace arena (~101 MB total)
  char* ws=(char*)d_ws; size_t off=0;
  auto A=[&](size_t bytes)->char*{ char* p=ws+off; off+=(bytes+255)&~(size_t)255; return p; };
  float* tok     =(float*)A((size_t)NBATCH*H*4);
  float* gm      =(float*)A((size_t)NBATCH*H*4);
  float* filt    =(float*)A((size_t)NBATCH*H*4);
  float* hh      =(float*)A((size_t)NBATCH*MDIM*4);
  float* uesel   =(float*)A((size_t)NBATCH*H*4);
  float* enh     =(float*)A((size_t)NBATCH*H*4);
  float* irep    =(float*)A((size_t)NI*H*4);             // 8 MB
  float* alltok  =(float*)A((size_t)NU*H*4);
  float* usertok =(float*)A((size_t)NU*H*4);
  float* urep    =(float*)A((size_t)NU*H*4);
  float* u1      =(float*)A((size_t)NU*H*4);
  float* u2      =(float*)A((size_t)NU*H*4);
  float* big     =(float*)A((size_t)16384000*4);         // 64 MB region, time-shared:
  float* partials=big;                                   //  phase A: 256*64*512 f (32 MB)
  float* partial2=big+8388608;                           //  phase A: 16*32768 f (2 MB)
  float* sim     =big;                                   //  phase B: 8,000,000 f
  float* dense   =big+8000000;                           //  phase B: 8,000,000 f
  float* Att     =big;                                   //  phase C: 8,192,000 f
  float* i1      =big+8192000;                           //  phase C: 8,192,000 f
  float* tv      =(float*)A((size_t)NU*KTOP*4);
  int*   ti      =(int*)  A((size_t)NU*KTOP*4);
  int*   rowsA   =(int*)  A((size_t)NEDGE*4);
  int*   colsA   =(int*)  A((size_t)NEDGE*4);
  float* valsA   =(float*)A((size_t)NEDGE*4);
  float* v_u     =(float*)A((size_t)NEDGE*4);
  float* v_i     =(float*)A((size_t)NEDGE*4);
  int*   ebr     =(int*)  A((size_t)NEDGE*4);
  int*   ebc     =(int*)  A((size_t)NEDGE*4);
  int*   row_ptr =(int*)  A((size_t)(NU+1)*4);
  int*   col_ptr =(int*)  A((size_t)(NE+1)*4);
  // contiguous zero block
  size_t zb_bytes=(size_t)(NU+NE)*4*3+256;
  char*  zb      =A(zb_bytes);
  float* seg_r   =(float*)zb;
  float* seg_c   =seg_r+NU;
  int*   row_cnt =(int*)(seg_c+NE);
  int*   col_cnt =row_cnt+NU;
  int*   fr      =col_cnt+NE;
  int*   fc      =fr+NU;
  float* loss_acc=(float*)(fc+NE);
  int*   inv     =(int*)  A((size_t)NE*4);
  float* sysf    =(float*)A((size_t)NBATCH*H*4);
  float* qbuf    =(float*)A((size_t)NBATCH*MDIM*4);
  float* p1buf   =(float*)A((size_t)NBATCH*H*4);
  float* p2buf   =(float*)A((size_t)NBATCH*P2N*4);
  (void)ws_size; (void)n_in; (void)in_sizes; (void)out_size;

  dim3 g642(NBATCH,2);

  // dense front-end
  k_tok  <<<g642,256,0,stream>>>(tok_emb,tp_w,tp_b,tok);
  k_gm   <<<g642,256,0,stream>>>(sysid,tok,gm);
  k_filt <<<g642,256,0,stream>>>(gm,trans_w,trans_b,pa,filt);
  k_hh   <<<NBATCH,256,0,stream>>>(filt,mw1,mb1,hh);
  k_ue   <<<g642,256,0,stream>>>(sysid,user_emb,uesel);
  k_ebias<<<g642,256,0,stream>>>(uesel,mb2,enh);
  k_big  <<<dim3(256,8),256,0,stream>>>(hh,uesel,mw2,partials);
  k_red1 <<<2048,256,0,stream>>>(partials,partial2);
  k_red2 <<<128,256,0,stream>>>(partial2,enh);

  hipMemcpyAsync(alltok,user_emb,(size_t)NU*H*4,hipMemcpyDeviceToDevice,stream);
  k_scatter_enh<<<g642,256,0,stream>>>(sysid,enh,alltok);
  hipMemsetAsync(usertok,0,(size_t)NU*H*4,stream);
  k_user_tok<<<g642,256,0,stream>>>(sysid,gm,trt_w,trt_b,pa,usertok);

  // similarity
  k_gemm<0,false,false><<<dim3(8,32),256,0,stream>>>(alltok,sw1,nullptr,nullptr,urep,NU,H,H);
  k_gemm<0,false,true> <<<dim3(8,63),256,0,stream>>>(node_emb,sw2,nullptr,itemid,irep,NI,H,H);
  k_rownorm<<<NU,256,0,stream>>>(urep);
  k_rownorm<<<NI,256,0,stream>>>(irep);
  k_gemm<2,true,false><<<dim3(63,32),256,0,stream>>>(urep,irep,nullptr,nullptr,sim,NU,NI,H);
  k_topk<<<NU,256,0,stream>>>(sim,tv,ti);

  // edges + CSR
  hipMemsetAsync(zb,0,zb_bytes,stream);
  k_edges<<<(NEDGE+255)/256,256,0,stream>>>(adj_row,adj_col,adj_val,itemid,tv,ti,
                                            rowsA,colsA,valsA,seg_r,seg_c,row_cnt,col_cnt);
  k_scan<<<2,1024,0,stream>>>(row_cnt,row_ptr,col_cnt,col_ptr);
  k_fill<<<(NEDGE+255)/256,256,0,stream>>>(rowsA,colsA,row_ptr,col_ptr,fr,fc,ebr,ebc);
  k_vuvi<<<(NEDGE+255)/256,256,0,stream>>>(rowsA,colsA,valsA,seg_r,seg_c,v_u,v_i);

  // loss (consumes sim+dense, must finish before Att/i1 reuse the region)
  hipMemsetAsync(inv,0xFF,(size_t)NE*4,stream);
  k_inv<<<(NI+255)/256,256,0,stream>>>(itemid,inv);
  hipMemsetAsync(dense,0,(size_t)8000000*4,stream);
  k_dense<<<(NNZ+255)/256,256,0,stream>>>(adj_row,adj_col,adj_val,inv,dense);
  k_loss<<<2048,256,0,stream>>>(sim,dense,loss_acc);
  k_loss_write<<<1,1,0,stream>>>(loss_acc,out_loss);

  // propagation
  k_spmm_u <<<NU,256,0,stream>>>(row_ptr,ebr,colsA,v_u,node_emb,usertok,u1);
  k_spmm_i1<<<NE,256,0,stream>>>(col_ptr,ebc,rowsA,v_i,alltok,usertok,node_emb,Att,i1);
  k_spmm_u <<<NU,256,0,stream>>>(row_ptr,ebr,colsA,v_u,i1,usertok,u2);
  k_spmm_i2<<<NE,256,0,stream>>>(col_ptr,ebc,rowsA,v_i,u1,Att,i1,node_emb,out_item);

  // prompt head
  k_sysfin<<<g642,256,0,stream>>>(sysid,alltok,u1,u2,sysf);
  k_q  <<<NBATCH,256,0,stream>>>(sysf,p1w1,p1b1,qbuf);
  k_p1 <<<g642,256,0,stream>>>(qbuf,p1w2,p1b2,sysf,p1buf);
  k_gemm<0,false,false><<<dim3(192,1),256,0,stream>>>(p1buf,p2w,p2b,nullptr,p2buf,NBATCH,P2N,H);
  k_perm<<<PROMPT_N/256,256,0,stream>>>(p2buf,out_prompt);
}

// Round 3
// 905.905 us; speedup vs baseline: 1.0554x; 1.0209x over previous
//
#include <hip/hip_runtime.h>

#define H     512
#define THD   768
#define MDIM  256
#define NE    16000
#define NU    2000
#define NI    4000
#define NNZ   40000
#define KTOP  10
#define NBATCH 64
#define NEDGE 60000          // NNZ + NU*KTOP
#define GAMA  0.1f
#define P2N   12288          // NL*NB*H
#define PROMPT_N 786432      // 24*64*512

__device__ __forceinline__ float sigmoidf(float x){ return 1.0f/(1.0f+expf(-x)); }

// ---------- small dense kernels (64 rows) ----------
__global__ void k_tok(const float* __restrict__ A, const float* __restrict__ W,
                      const float* __restrict__ bias, float* __restrict__ C){
  int b=blockIdx.x, c=blockIdx.y*256+threadIdx.x;
  const float* a=A+b*THD; float s=bias[c];
  for(int k=0;k<THD;k++) s+=a[k]*W[k*H+c];
  C[b*H+c]=s;
}

__global__ void k_gm(const int* __restrict__ sysid, const float* __restrict__ tok,
                     float* __restrict__ gm){
  int b=blockIdx.x, c=blockIdx.y*256+threadIdx.x;
  int sid=sysid[b]; float s=0.f, cnt=0.f;
  for(int j=0;j<NBATCH;j++){ if(sysid[j]==sid){ s+=tok[j*H+c]; cnt+=1.f; } }
  gm[b*H+c]=s/cnt;
}

__global__ void k_filt(const float* __restrict__ gm, const float* __restrict__ W,
                       const float* __restrict__ bias, const float* __restrict__ pa,
                       float* __restrict__ filt){
  int b=blockIdx.x, c=blockIdx.y*256+threadIdx.x;
  const float* a=gm+b*H; float s=bias[c];
  for(int k=0;k<H;k++) s+=a[k]*W[k*H+c];
  float al=pa[0]; float pr = (s>=0.f)? s : al*s;
  filt[b*H+c]=pr*gm[b*H+c];
}

__global__ void k_hh(const float* __restrict__ filt, const float* __restrict__ W,
                     const float* __restrict__ bias, float* __restrict__ hh){
  int b=blockIdx.x, m=threadIdx.x;
  const float* a=filt+b*H; float s=bias[m];
  for(int k=0;k<H;k++) s+=a[k]*W[k*MDIM+m];
  hh[b*MDIM+m]=fmaxf(s,0.f);
}

__global__ void k_ue(const int* __restrict__ sysid, const float* __restrict__ ue,
                     float* __restrict__ uesel){
  int b=blockIdx.x, c=blockIdx.y*256+threadIdx.x;
  uesel[b*H+c]=ue[(size_t)sysid[b]*H+c];
}

// transposed user-embedding selection: ueT[h][b] = ue[sysid[b]][h]
__global__ void k_uet(const int* __restrict__ sysid, const float* __restrict__ ue,
                      float* __restrict__ ueT){
  int idx=blockIdx.x*256+threadIdx.x;   // 0..32767
  int h=idx>>6, b=idx&63;
  ueT[idx]=ue[(size_t)sysid[b]*H+h];
}

// enhanced bias term: enh[b,k] = sum_h uesel[b,h]*mb2[h*H+k]
__global__ void k_ebias(const float* __restrict__ uesel, const float* __restrict__ mb2,
                        float* __restrict__ enh){
  int b=blockIdx.x, k=blockIdx.y*256+threadIdx.x;
  const float* u=uesel+b*H; float s=0.f;
  for(int h=0;h<H;h++) s+=u[h]*mb2[(size_t)h*H+k];
  enh[b*H+k]=s;
}

// ---------- big hypernet contraction ----------
// partials[m][b][k] = hh[b,m] * sum_h ueT[h,b]*W2[m,h*H+k]
// hh factored OUT of the h-sum -> A-tile is m-independent, coalesced copy of ueT.
// grid (256 m, 4 kt of 128) = 1024 blocks; 24 KB LDS; reg-prefetch double buffer.
#define HCH 32
__global__ __launch_bounds__(256) void k_big(const float* __restrict__ hh,
        const float* __restrict__ ueT, const float* __restrict__ w2,
        float* __restrict__ partials){
  __shared__ float a_lds[HCH][64];    // [h][b]
  __shared__ float w_lds[HCH][128];   // [h][k]
  int m=blockIdx.x;                   // 0..255
  int k0=blockIdx.y*128;              // 0,128,256,384
  int t=threadIdx.x;
  int tn=t&15, tm=t>>4;               // k-group (8 wide), b-group (4 wide)
  const float* w2m = w2 + (size_t)m*(size_t)(H*H);
  float4 ar0,ar1,wr0,wr1,wr2,wr3;
  // prefetch chunk 0
  ar0=*(const float4*)(ueT + (size_t)t*4);
  ar1=*(const float4*)(ueT + (size_t)(t+256)*4);
  {
    int i0=t, i1=t+256, i2=t+512, i3=t+768;
    wr0=*(const float4*)(w2m+(size_t)(i0>>5)*H+k0+(i0&31)*4);
    wr1=*(const float4*)(w2m+(size_t)(i1>>5)*H+k0+(i1&31)*4);
    wr2=*(const float4*)(w2m+(size_t)(i2>>5)*H+k0+(i2&31)*4);
    wr3=*(const float4*)(w2m+(size_t)(i3>>5)*H+k0+(i3&31)*4);
  }
  float acc[4][8]={};
  for(int hc=0;hc<16;hc++){
    __syncthreads();                  // prev compute done, LDS free
    *(float4*)((float*)a_lds + t*4)      =ar0;
    *(float4*)((float*)a_lds + (t+256)*4)=ar1;
    *(float4*)((float*)w_lds + t*4)      =wr0;
    *(float4*)((float*)w_lds + (t+256)*4)=wr1;
    *(float4*)((float*)w_lds + (t+512)*4)=wr2;
    *(float4*)((float*)w_lds + (t+768)*4)=wr3;
    __syncthreads();
    if(hc<15){
      int h0=(hc+1)*HCH;
      ar0=*(const float4*)(ueT + (size_t)h0*64 + t*4);
      ar1=*(const float4*)(ueT + (size_t)h0*64 + (t+256)*4);
      int i0=t, i1=t+256, i2=t+512, i3=t+768;
      wr0=*(const float4*)(w2m+(size_t)(h0+(i0>>5))*H+k0+(i0&31)*4);
      wr1=*(const float4*)(w2m+(size_t)(h0+(i1>>5))*H+k0+(i1&31)*4);
      wr2=*(const float4*)(w2m+(size_t)(h0+(i2>>5))*H+k0+(i2&31)*4);
      wr3=*(const float4*)(w2m+(size_t)(h0+(i3>>5))*H+k0+(i3&31)*4);
    }
    #pragma unroll
    for(int hl=0;hl<HCH;hl++){
      float4 a4 =*(const float4*)&a_lds[hl][tm*4];
      float4 w4a=*(const float4*)&w_lds[hl][tn*8];
      float4 w4b=*(const float4*)&w_lds[hl][tn*8+4];
      acc[0][0]+=a4.x*w4a.x; acc[0][1]+=a4.x*w4a.y; acc[0][2]+=a4.x*w4a.z; acc[0][3]+=a4.x*w4a.w;
      acc[0][4]+=a4.x*w4b.x; acc[0][5]+=a4.x*w4b.y; acc[0][6]+=a4.x*w4b.z; acc[0][7]+=a4.x*w4b.w;
      acc[1][0]+=a4.y*w4a.x; acc[1][1]+=a4.y*w4a.y; acc[1][2]+=a4.y*w4a.z; acc[1][3]+=a4.y*w4a.w;
      acc[1][4]+=a4.y*w4b.x; acc[1][5]+=a4.y*w4b.y; acc[1][6]+=a4.y*w4b.z; acc[1][7]+=a4.y*w4b.w;
      acc[2][0]+=a4.z*w4a.x; acc[2][1]+=a4.z*w4a.y; acc[2][2]+=a4.z*w4a.z; acc[2][3]+=a4.z*w4a.w;
      acc[2][4]+=a4.z*w4b.x; acc[2][5]+=a4.z*w4b.y; acc[2][6]+=a4.z*w4b.z; acc[2][7]+=a4.z*w4b.w;
      acc[3][0]+=a4.w*w4a.x; acc[3][1]+=a4.w*w4a.y; acc[3][2]+=a4.w*w4a.z; acc[3][3]+=a4.w*w4a.w;
      acc[3][4]+=a4.w*w4b.x; acc[3][5]+=a4.w*w4b.y; acc[3][6]+=a4.w*w4b.z; acc[3][7]+=a4.w*w4b.w;
    }
  }
  #pragma unroll
  for(int bi=0;bi<4;bi++){
    int bb=tm*4+bi;
    float hv=hh[bb*MDIM+m];
    float* p=partials+((size_t)m*NBATCH+bb)*H+k0+tn*8;
    *(float4*)p    =make_float4(acc[bi][0]*hv,acc[bi][1]*hv,acc[bi][2]*hv,acc[bi][3]*hv);
    *(float4*)(p+4)=make_float4(acc[bi][4]*hv,acc[bi][5]*hv,acc[bi][6]*hv,acc[bi][7]*hv);
  }
}

// two-stage reduction over the 256 m-partials (stage1: 2048 blocks, coalesced)
__global__ void k_red1(const float* __restrict__ partials, float* __restrict__ partial2){
  int idx=blockIdx.x*256+threadIdx.x;      // 0..524287
  int g=idx>>15, col=idx&32767;            // g: 16 groups of 16 m's
  const float* p=partials+(size_t)g*16*32768+col;
  float s=0.f;
  #pragma unroll
  for(int m=0;m<16;m++) s+=p[(size_t)m*32768];
  partial2[idx]=s;
}
__global__ void k_red2(const float* __restrict__ partial2, float* __restrict__ enh){
  int idx=blockIdx.x*256+threadIdx.x;      // 0..32767
  float s=enh[idx];
  #pragma unroll
  for(int g=0;g<16;g++) s+=partial2[(size_t)g*32768+idx];
  enh[idx]=s;
}

__global__ void k_scatter_enh(const int* __restrict__ sysid, const float* __restrict__ enh,
                              float* __restrict__ alltok){
  int b=blockIdx.x, c=blockIdx.y*256+threadIdx.x;
  alltok[(size_t)sysid[b]*H+c]=enh[b*H+c];  // duplicate sysids write identical values
}

__global__ void k_user_tok(const int* __restrict__ sysid, const float* __restrict__ gm,
                           const float* __restrict__ W, const float* __restrict__ bias,
                           const float* __restrict__ pa, float* __restrict__ usertok){
  int b=blockIdx.x, c=blockIdx.y*256+threadIdx.x;
  const float* a=gm+b*H; float s=bias[c];
  for(int k=0;k<H;k++) s+=a[k]*W[k*H+c];
  float al=pa[0]; float pr=(s>=0.f)? s : al*s;
  usertok[(size_t)sysid[b]*H+c]=pr*gm[b*H+c];
}

// ---------- tiled fp32 GEMM, BM=BN=64, BK=32 (small-matrix helper) ----------
template<int EPI, bool NT, bool AIDX>
__global__ __launch_bounds__(256) void k_gemm(const float* __restrict__ A,
        const float* __restrict__ Bm, const float* __restrict__ bias,
        const int* __restrict__ aidx, float* __restrict__ C, int M, int N, int K){
  __shared__ float As[32][68];
  __shared__ float Bs[32][68];
  int n0=blockIdx.x*64, m0=blockIdx.y*64;
  int t=threadIdx.x;
  int tn=t&15, tm=t>>4;
  float acc[4][4]={};
  for(int kt=0;kt<K;kt+=32){
    #pragma unroll
    for(int i=0;i<2;i++){
      int idx=t+i*256; int r=idx>>3, q=idx&7;
      int grow=m0+r;
      float4 v=make_float4(0.f,0.f,0.f,0.f);
      if(grow<M){
        const float* arow=A+(size_t)(AIDX? aidx[grow]:grow)*K;
        v=*(const float4*)(arow+kt+q*4);
      }
      As[q*4+0][r]=v.x; As[q*4+1][r]=v.y; As[q*4+2][r]=v.z; As[q*4+3][r]=v.w;
    }
    if(!NT){
      #pragma unroll
      for(int i=0;i<2;i++){
        int idx=t+i*256; int r=idx>>4, q=idx&15;   // N assumed multiple of 64 here
        float4 v=*(const float4*)(Bm+(size_t)(kt+r)*N+n0+q*4);
        *(float4*)&Bs[r][q*4]=v;
      }
    } else {
      #pragma unroll
      for(int i=0;i<2;i++){
        int idx=t+i*256; int r=idx>>3, q=idx&7;
        int gn=n0+r;
        float4 v=make_float4(0.f,0.f,0.f,0.f);
        if(gn<N) v=*(const float4*)(Bm+(size_t)gn*K+kt+q*4);
        Bs[q*4+0][r]=v.x; Bs[q*4+1][r]=v.y; Bs[q*4+2][r]=v.z; Bs[q*4+3][r]=v.w;
      }
    }
    __syncthreads();
    #pragma unroll 8
    for(int k=0;k<32;k++){
      float4 a4=*(const float4*)&As[k][tm*4];
      float4 b4=*(const float4*)&Bs[k][tn*4];
      acc[0][0]+=a4.x*b4.x; acc[0][1]+=a4.x*b4.y; acc[0][2]+=a4.x*b4.z; acc[0][3]+=a4.x*b4.w;
      acc[1][0]+=a4.y*b4.x; acc[1][1]+=a4.y*b4.y; acc[1][2]+=a4.y*b4.z; acc[1][3]+=a4.y*b4.w;
      acc[2][0]+=a4.z*b4.x; acc[2][1]+=a4.z*b4.y; acc[2][2]+=a4.z*b4.z; acc[2][3]+=a4.z*b4.w;
      acc[3][0]+=a4.w*b4.x; acc[3][1]+=a4.w*b4.y; acc[3][2]+=a4.w*b4.z; acc[3][3]+=a4.w*b4.w;
    }
    __syncthreads();
  }
  #pragma unroll
  for(int bi=0;bi<4;bi++){
    int row=m0+tm*4+bi; if(row>=M) continue;
    #pragma unroll
    for(int ki=0;ki<4;ki++){
      int col=n0+tn*4+ki; if(col>=N) continue;
      float v=acc[bi][ki];
      if(EPI==0){ if(bias) v+=bias[col]; }
      else { v=sigmoidf(v); }
      C[(size_t)row*N+col]=v;
    }
  }
}

// ---------- 128x128-tile sim GEMM: C = sigmoid(A[M,512] @ B[N,512]^T) ----------
__global__ __launch_bounds__(512) void k_gemm_sim(const float* __restrict__ A,
        const float* __restrict__ Bm, float* __restrict__ C, int M, int N){
  __shared__ float As[32][132];
  __shared__ float Bs[32][132];
  int n0=blockIdx.x*128, m0=blockIdx.y*128;
  int t=threadIdx.x;
  int tn=t&31, tm=t>>5;               // n-group (4 wide), m-group (8 wide)
  float acc[8][4]={};
  for(int kt=0;kt<H;kt+=32){
    #pragma unroll
    for(int i=0;i<2;i++){
      int idx=t+i*512; int r=idx>>3, q=idx&7;
      int gr=m0+r;
      float4 v=make_float4(0.f,0.f,0.f,0.f);
      if(gr<M) v=*(const float4*)(A+(size_t)gr*H+kt+q*4);
      As[q*4+0][r]=v.x; As[q*4+1][r]=v.y; As[q*4+2][r]=v.z; As[q*4+3][r]=v.w;
    }
    #pragma unroll
    for(int i=0;i<2;i++){
      int idx=t+i*512; int r=idx>>3, q=idx&7;
      int gn=n0+r;
      float4 v=make_float4(0.f,0.f,0.f,0.f);
      if(gn<N) v=*(const float4*)(Bm+(size_t)gn*H+kt+q*4);
      Bs[q*4+0][r]=v.x; Bs[q*4+1][r]=v.y; Bs[q*4+2][r]=v.z; Bs[q*4+3][r]=v.w;
    }
    __syncthreads();
    #pragma unroll 8
    for(int k=0;k<32;k++){
      float4 a0=*(const float4*)&As[k][tm*8];
      float4 a1=*(const float4*)&As[k][tm*8+4];
      float4 b0=*(const float4*)&Bs[k][tn*4];
      acc[0][0]+=a0.x*b0.x; acc[0][1]+=a0.x*b0.y; acc[0][2]+=a0.x*b0.z; acc[0][3]+=a0.x*b0.w;
      acc[1][0]+=a0.y*b0.x; acc[1][1]+=a0.y*b0.y; acc[1][2]+=a0.y*b0.z; acc[1][3]+=a0.y*b0.w;
      acc[2][0]+=a0.z*b0.x; acc[2][1]+=a0.z*b0.y; acc[2][2]+=a0.z*b0.z; acc[2][3]+=a0.z*b0.w;
      acc[3][0]+=a0.w*b0.x; acc[3][1]+=a0.w*b0.y; acc[3][2]+=a0.w*b0.z; acc[3][3]+=a0.w*b0.w;
      acc[4][0]+=a1.x*b0.x; acc[4][1]+=a1.x*b0.y; acc[4][2]+=a1.x*b0.z; acc[4][3]+=a1.x*b0.w;
      acc[5][0]+=a1.y*b0.x; acc[5][1]+=a1.y*b0.y; acc[5][2]+=a1.y*b0.z; acc[5][3]+=a1.y*b0.w;
      acc[6][0]+=a1.z*b0.x; acc[6][1]+=a1.z*b0.y; acc[6][2]+=a1.z*b0.z; acc[6][3]+=a1.z*b0.w;
      acc[7][0]+=a1.w*b0.x; acc[7][1]+=a1.w*b0.y; acc[7][2]+=a1.w*b0.z; acc[7][3]+=a1.w*b0.w;
    }
    __syncthreads();
  }
  #pragma unroll
  for(int mi=0;mi<8;mi++){
    int row=m0+tm*8+mi; if(row>=M) continue;
    #pragma unroll
    for(int nj=0;nj<4;nj++){
      int col=n0+tn*4+nj; if(col>=N) continue;
      C[(size_t)row*N+col]=sigmoidf(acc[mi][nj]);
    }
  }
}

__global__ __launch_bounds__(256) void k_rownorm(float* __restrict__ X){
  int r=blockIdx.x, t=threadIdx.x;
  float v1=X[(size_t)r*H+t], v2=X[(size_t)r*H+t+256];
  float ss=v1*v1+v2*v2;
  for(int o=32;o;o>>=1) ss+=__shfl_xor(ss,o);
  __shared__ float red[4];
  if((t&63)==0) red[t>>6]=ss;
  __syncthreads();
  float tot=red[0]+red[1]+red[2]+red[3];
  float nrm=fmaxf(sqrtf(tot),1e-12f);
  X[(size_t)r*H+t]=v1/nrm; X[(size_t)r*H+t+256]=v2/nrm;
}

// ---------- top-k (lax.top_k semantics: desc values, ties -> smaller index) ----------
__global__ __launch_bounds__(256) void k_topk(const float* __restrict__ sim,
        float* __restrict__ tv, int* __restrict__ ti){
  __shared__ float vals[NI];
  __shared__ float rv[256];
  __shared__ int   ri[256];
  int u=blockIdx.x, t=threadIdx.x;
  for(int i=t;i<NI;i+=256) vals[i]=sim[(size_t)u*NI+i];
  __syncthreads();
  for(int k=0;k<KTOP;k++){
    float bv=-1e30f; int bi=NI;
    for(int i=t;i<NI;i+=256){
      float v=vals[i];
      if(v>bv || (v==bv && i<bi)){ bv=v; bi=i; }
    }
    rv[t]=bv; ri[t]=bi; __syncthreads();
    for(int s=128;s>0;s>>=1){
      if(t<s){
        float ov=rv[t+s]; int oi=ri[t+s];
        if(ov>rv[t] || (ov==rv[t] && oi<ri[t])){ rv[t]=ov; ri[t]=oi; }
      }
      __syncthreads();
    }
    if(t==0){ tv[u*KTOP+k]=rv[0]; ti[u*KTOP+k]=ri[0]; vals[ri[0]]=-1e30f; }
    __syncthreads();
  }
}

// ---------- edges, CSR, normalizers ----------
__global__ void k_edges(const int* __restrict__ adj_row, const int* __restrict__ adj_col,
        const float* __restrict__ adj_val, const int* __restrict__ itemid,
        const float* __restrict__ tv, const int* __restrict__ ti,
        int* __restrict__ rows, int* __restrict__ cols, float* __restrict__ vals,
        float* __restrict__ seg_r, float* __restrict__ seg_c,
        int* __restrict__ row_cnt, int* __restrict__ col_cnt){
  int e=blockIdx.x*256+threadIdx.x; if(e>=NEDGE) return;
  int r,c; float v;
  if(e<NNZ){ r=adj_row[e]; c=adj_col[e]; v=adj_val[e]; }
  else { int x=e-NNZ; int u=x/KTOP; r=u; c=itemid[ti[x]]; v=tv[x]; }
  rows[e]=r; cols[e]=c; vals[e]=v;
  atomicAdd(&seg_r[r],v); atomicAdd(&seg_c[c],v);
  atomicAdd(&row_cnt[r],1); atomicAdd(&col_cnt[c],1);
}

__global__ __launch_bounds__(1024) void k_scan(const int* __restrict__ rc, int* __restrict__ rp,
        const int* __restrict__ cc, int* __restrict__ cp){
  const int* cnt; int* ptr; int n;
  if(blockIdx.x==0){ cnt=rc; ptr=rp; n=NU; } else { cnt=cc; ptr=cp; n=NE; }
  int t=threadIdx.x;
  int chunk=(n+1023)>>10;
  int base=t*chunk;
  int s=0;
  for(int i=0;i<chunk;i++){ int j=base+i; if(j<n) s+=cnt[j]; }
  __shared__ int buf[1024];
  buf[t]=s; __syncthreads();
  for(int off=1;off<1024;off<<=1){
    int y=(t>=off)? buf[t-off]:0;
    __syncthreads();
    buf[t]+=y;
    __syncthreads();
  }
  int run=buf[t]-s;
  for(int i=0;i<chunk;i++){ int j=base+i; if(j<n){ ptr[j]=run; run+=cnt[j]; } }
  if(t==1023) ptr[n]=buf[1023];
}

__global__ void k_fill(const int* __restrict__ rows, const int* __restrict__ cols,
        const int* __restrict__ row_ptr, const int* __restrict__ col_ptr,
        int* __restrict__ fr, int* __restrict__ fc,
        int* __restrict__ ebr, int* __restrict__ ebc){
  int e=blockIdx.x*256+threadIdx.x; if(e>=NEDGE) return;
  int r=rows[e], c=cols[e];
  ebr[row_ptr[r]+atomicAdd(&fr[r],1)]=e;
  ebc[col_ptr[c]+atomicAdd(&fc[c],1)]=e;
}

__global__ void k_vuvi(const int* __restrict__ rows, const int* __restrict__ cols,
        const float* __restrict__ vals, const float* __restrict__ seg_r,
        const float* __restrict__ seg_c, float* __restrict__ v_u, float* __restrict__ v_i){
  int e=blockIdx.x*256+threadIdx.x; if(e>=NEDGE) return;
  v_u[e]=vals[e]/seg_r[rows[e]];
  v_i[e]=vals[e]/seg_c[cols[e]];
}

// ---------- SpMM kernels (CSR, deterministic per-row loop) ----------
__global__ __launch_bounds__(256) void k_spmm_u(const int* __restrict__ row_ptr,
        const int* __restrict__ ebr, const int* __restrict__ cols,
        const float* __restrict__ v_u, const float* __restrict__ X,
        const float* __restrict__ usertok, float* __restrict__ out){
  int u=blockIdx.x, t=threadIdx.x;
  float a0=0.f,a1=0.f;
  int s=row_ptr[u], e1=row_ptr[u+1];
  for(int j=s;j<e1;j++){
    int e=ebr[j]; float v=v_u[e];
    const float* xr=X+(size_t)cols[e]*H;
    a0+=v*xr[t]; a1+=v*xr[t+256];
  }
  float u0=usertok[(size_t)u*H+t], u1v=usertok[(size_t)u*H+t+256];
  out[(size_t)u*H+t]=a0+a0*u0; out[(size_t)u*H+t+256]=a1+a1*u1v;
}

__global__ __launch_bounds__(256) void k_spmm_i1(const int* __restrict__ col_ptr,
        const int* __restrict__ ebc, const int* __restrict__ rows,
        const float* __restrict__ v_i, const float* __restrict__ alltok,
        const float* __restrict__ usertok, const float* __restrict__ i0,
        float* __restrict__ Att, float* __restrict__ i1){
  int i=blockIdx.x, t=threadIdx.x;
  float aA0=0.f,aA1=0.f,aU0=0.f,aU1=0.f;
  int s=col_ptr[i], e1=col_ptr[i+1];
  for(int j=s;j<e1;j++){
    int e=ebc[j]; float v=v_i[e]; int r=rows[e];
    const float* ur=usertok+(size_t)r*H;
    const float* ar=alltok+(size_t)r*H;
    aA0+=v*ur[t]; aA1+=v*ur[t+256];
    aU0+=v*ar[t]; aU1+=v*ar[t+256];
  }
  size_t o=(size_t)i*H;
  Att[o+t]=aA0; Att[o+t+256]=aA1;
  i1[o+t]=aU0+aA0*i0[o+t]; i1[o+t+256]=aU1+aA1*i0[o+t+256];
}

__global__ __launch_bounds__(256) void k_spmm_i2(const int* __restrict__ col_ptr,
        const int* __restrict__ ebc, const int* __restrict__ rows,
        const float* __restrict__ v_i, const float* __restrict__ u1,
        const float* __restrict__ Att, const float* __restrict__ i1,
        const float* __restrict__ i0, float* __restrict__ item_out){
  int i=blockIdx.x, t=threadIdx.x;
  float a0=0.f,a1=0.f;
  int s=col_ptr[i], e1=col_ptr[i+1];
  for(int j=s;j<e1;j++){
    int e=ebc[j]; float v=v_i[e];
    const float* ur=u1+(size_t)rows[e]*H;
    a0+=v*ur[t]; a1+=v*ur[t+256];
  }
  size_t o=(size_t)i*H;
  float i2a=a0+Att[o+t]*i1[o+t];
  float i2b=a1+Att[o+t+256]*i1[o+t+256];
  item_out[o+t]=(i0[o+t]+i1[o+t]+i2a)/3.0f;
  item_out[o+t+256]=(i0[o+t+256]+i1[o+t+256]+i2b)/3.0f;
}

// ---------- loss ----------
__global__ void k_inv(const int* __restrict__ itemid, int* __restrict__ inv){
  int j=blockIdx.x*256+threadIdx.x; if(j<NI) inv[itemid[j]]=j;
}
__global__ void k_dense(const int* __restrict__ adj_row, const int* __restrict__ adj_col,
        const float* __restrict__ adj_val, const int* __restrict__ inv,
        float* __restrict__ dense){
  int e=blockIdx.x*256+threadIdx.x; if(e>=NNZ) return;
  int ic=inv[adj_col[e]];
  if(ic>=0) atomicAdd(&dense[(size_t)adj_row[e]*NI+ic],adj_val[e]);
}
__global__ __launch_bounds__(256) void k_loss(const float* __restrict__ sim,
        const float* __restrict__ dense, float* __restrict__ acc){
  size_t n4=(size_t)NU*NI/4;
  float s=0.f;
  for(size_t i=(size_t)blockIdx.x*256+threadIdx.x; i<n4; i+=(size_t)gridDim.x*256){
    float4 a=((const float4*)sim)[i], d=((const float4*)dense)[i];
    float dx=a.x-d.x, dy=a.y-d.y, dz=a.z-d.z, dw=a.w-d.w;
    s+=dx*dx+dy*dy+dz*dz+dw*dw;
  }
  __shared__ float red[256];
  red[threadIdx.x]=s; __syncthreads();
  for(int o=128;o;o>>=1){ if(threadIdx.x<o) red[threadIdx.x]+=red[threadIdx.x+o]; __syncthreads(); }
  if(threadIdx.x==0) atomicAdd(acc,red[0]);
}
__global__ void k_loss_write(const float* __restrict__ acc, float* __restrict__ out){
  out[0]=GAMA*(acc[0]/(float)((size_t)NU*NI));
}

// ---------- prompt head ----------
__global__ void k_sysfin(const int* __restrict__ sysid, const float* __restrict__ u0,
        const float* __restrict__ u1, const float* __restrict__ u2, float* __restrict__ sysf){
  int b=blockIdx.x, c=blockIdx.y*256+threadIdx.x;
  size_t o=(size_t)sysid[b]*H+c;
  sysf[b*H+c]=(u0[o]+u1[o]+u2[o])/3.0f;
}
__global__ void k_q(const float* __restrict__ sysf, const float* __restrict__ W,
        const float* __restrict__ bias, float* __restrict__ q){
  int b=blockIdx.x, m=threadIdx.x;
  const float* a=sysf+b*H; float s=bias[m];
  for(int k=0;k<H;k++) s+=a[k]*W[k*MDIM+m];
  q[b*MDIM+m]=fmaxf(s,0.f);
}
__global__ void k_p1(const float* __restrict__ q, const float* __restrict__ W,
        const float* __restrict__ bias, const float* __restrict__ sysf, float* __restrict__ p1){
  int b=blockIdx.x, c=blockIdx.y*256+threadIdx.x;
  const float* a=q+b*MDIM; float s=bias[c];
  for(int k=0;k<MDIM;k++) s+=a[k]*W[k*H+c];
  p1[b*H+c]=s+sysf[b*H+c];
}
__global__ void k_perm(const float* __restrict__ p2, float* __restrict__ out){
  int idx=blockIdx.x*256+threadIdx.x;       // 0..786431
  int x=idx&511;
  int b=(idx>>9)&63;
  int c=idx>>15;                            // 0..23
  out[idx]=p2[(size_t)b*P2N+c*512+x];
}

// ---------- host ----------
extern "C" void kernel_launch(void* const* d_in, const int* in_sizes, int n_in,
                              void* d_out, int out_size, void* d_ws, size_t ws_size,
                              hipStream_t stream){
  const int*   sysid   =(const int*)  d_in[0];
  const int*   adj_row =(const int*)  d_in[1];
  const int*   adj_col =(const int*)  d_in[2];
  const int*   itemid  =(const int*)  d_in[3];
  const float* tok_emb =(const float*)d_in[4];
  const float* adj_val =(const float*)d_in[5];
  const float* node_emb=(const float*)d_in[6];
  const float* user_emb=(const float*)d_in[7];
  const float* tp_w    =(const float*)d_in[8];
  const float* tp_b    =(const float*)d_in[9];
  const float* trans_w =(const float*)d_in[10];
  const float* trans_b =(const float*)d_in[11];
  const float* trt_w   =(const float*)d_in[12];
  const float* trt_b   =(const float*)d_in[13];
  const float* mw1     =(const float*)d_in[14];
  const float* mb1     =(const float*)d_in[15];
  const float* mw2     =(const float*)d_in[16];
  const float* mb2     =(const float*)d_in[17];
  const float* sw1     =(const float*)d_in[18];
  const float* sw2     =(const float*)d_in[19];
  const float* p1w1    =(const float*)d_in[20];
  const float* p1b1    =(const float*)d_in[21];
  const float* p1w2    =(const float*)d_in[22];
  const float* p1b2    =(const float*)d_in[23];
  const float* p2w     =(const float*)d_in[24];
  const float* p2b     =(const float*)d_in[25];
  const float* pa      =(const float*)d_in[26];

  float* out_prompt=(float*)d_out;
  float* out_item  =out_prompt+PROMPT_N;
  float* out_loss  =out_item+(size_t)NE*H;

  // workspace arena (~101 MB total)
  char* ws=(char*)d_ws; size_t off=0;
  auto A=[&](size_t bytes)->char*{ char* p=ws+off; off+=(bytes+255)&~(size_t)255; return p; };
  float* tok     =(float*)A((size_t)NBATCH*H*4);
  float* gm      =(float*)A((size_t)NBATCH*H*4);
  float* filt    =(float*)A((size_t)NBATCH*H*4);
  float* hh      =(float*)A((size_t)NBATCH*MDIM*4);
  float* uesel   =(float*)A((size_t)NBATCH*H*4);
  float* ueT     =(float*)A((size_t)H*NBATCH*4);
  float* enh     =(float*)A((size_t)NBATCH*H*4);
  float* irep    =(float*)A((size_t)NI*H*4);             // 8 MB
  float* alltok  =(float*)A((size_t)NU*H*4);
  float* usertok =(float*)A((size_t)NU*H*4);
  float* urep    =(float*)A((size_t)NU*H*4);
  float* u1      =(float*)A((size_t)NU*H*4);
  float* u2      =(float*)A((size_t)NU*H*4);
  float* big     =(float*)A((size_t)16384000*4);         // 64 MB region, time-shared:
  float* partials=big;                                   //  phase A: 256*64*512 f (32 MB)
  float* partial2=big+8388608;                           //  phase A: 16*32768 f (2 MB)
  float* sim     =big;                                   //  phase B: 8,000,000 f
  float* dense   =big+8000000;                           //  phase B: 8,000,000 f
  float* Att     =big;                                   //  phase C: 8,192,000 f
  float* i1      =big+8192000;                           //  phase C: 8,192,000 f
  float* tv      =(float*)A((size_t)NU*KTOP*4);
  int*   ti      =(int*)  A((size_t)NU*KTOP*4);
  int*   rowsA   =(int*)  A((size_t)NEDGE*4);
  int*   colsA   =(int*)  A((size_t)NEDGE*4);
  float* valsA   =(float*)A((size_t)NEDGE*4);
  float* v_u     =(float*)A((size_t)NEDGE*4);
  float* v_i     =(float*)A((size_t)NEDGE*4);
  int*   ebr     =(int*)  A((size_t)NEDGE*4);
  int*   ebc     =(int*)  A((size_t)NEDGE*4);
  int*   row_ptr =(int*)  A((size_t)(NU+1)*4);
  int*   col_ptr =(int*)  A((size_t)(NE+1)*4);
  // contiguous zero block
  size_t zb_bytes=(size_t)(NU+NE)*4*3+256;
  char*  zb      =A(zb_bytes);
  float* seg_r   =(float*)zb;
  float* seg_c   =seg_r+NU;
  int*   row_cnt =(int*)(seg_c+NE);
  int*   col_cnt =row_cnt+NU;
  int*   fr      =col_cnt+NE;
  int*   fc      =fr+NU;
  float* loss_acc=(float*)(fc+NE);
  int*   inv     =(int*)  A((size_t)NE*4);
  float* sysf    =(float*)A((size_t)NBATCH*H*4);
  float* qbuf    =(float*)A((size_t)NBATCH*MDIM*4);
  float* p1buf   =(float*)A((size_t)NBATCH*H*4);
  float* p2buf   =(float*)A((size_t)NBATCH*P2N*4);
  (void)ws_size; (void)n_in; (void)in_sizes; (void)out_size;

  dim3 g642(NBATCH,2);

  // dense front-end
  k_tok  <<<g642,256,0,stream>>>(tok_emb,tp_w,tp_b,tok);
  k_gm   <<<g642,256,0,stream>>>(sysid,tok,gm);
  k_filt <<<g642,256,0,stream>>>(gm,trans_w,trans_b,pa,filt);
  k_hh   <<<NBATCH,256,0,stream>>>(filt,mw1,mb1,hh);
  k_ue   <<<g642,256,0,stream>>>(sysid,user_emb,uesel);
  k_uet  <<<128,256,0,stream>>>(sysid,user_emb,ueT);
  k_ebias<<<g642,256,0,stream>>>(uesel,mb2,enh);
  k_big  <<<dim3(256,4),256,0,stream>>>(hh,ueT,mw2,partials);
  k_red1 <<<2048,256,0,stream>>>(partials,partial2);
  k_red2 <<<128,256,0,stream>>>(partial2,enh);

  hipMemcpyAsync(alltok,user_emb,(size_t)NU*H*4,hipMemcpyDeviceToDevice,stream);
  k_scatter_enh<<<g642,256,0,stream>>>(sysid,enh,alltok);
  hipMemsetAsync(usertok,0,(size_t)NU*H*4,stream);
  k_user_tok<<<g642,256,0,stream>>>(sysid,gm,trt_w,trt_b,pa,usertok);

  // similarity
  k_gemm<0,false,false><<<dim3(8,32),256,0,stream>>>(alltok,sw1,nullptr,nullptr,urep,NU,H,H);
  k_gemm<0,false,true> <<<dim3(8,63),256,0,stream>>>(node_emb,sw2,nullptr,itemid,irep,NI,H,H);
  k_rownorm<<<NU,256,0,stream>>>(urep);
  k_rownorm<<<NI,256,0,stream>>>(irep);
  k_gemm_sim<<<dim3(32,16),512,0,stream>>>(urep,irep,sim,NU,NI);
  k_topk<<<NU,256,0,stream>>>(sim,tv,ti);

  // edges + CSR
  hipMemsetAsync(zb,0,zb_bytes,stream);
  k_edges<<<(NEDGE+255)/256,256,0,stream>>>(adj_row,adj_col,adj_val,itemid,tv,ti,
                                            rowsA,colsA,valsA,seg_r,seg_c,row_cnt,col_cnt);
  k_scan<<<2,1024,0,stream>>>(row_cnt,row_ptr,col_cnt,col_ptr);
  k_fill<<<(NEDGE+255)/256,256,0,stream>>>(rowsA,colsA,row_ptr,col_ptr,fr,fc,ebr,ebc);
  k_vuvi<<<(NEDGE+255)/256,256,0,stream>>>(rowsA,colsA,valsA,seg_r,seg_c,v_u,v_i);

  // loss (consumes sim+dense, must finish before Att/i1 reuse the region)
  hipMemsetAsync(inv,0xFF,(size_t)NE*4,stream);
  k_inv<<<(NI+255)/256,256,0,stream>>>(itemid,inv);
  hipMemsetAsync(dense,0,(size_t)8000000*4,stream);
  k_dense<<<(NNZ+255)/256,256,0,stream>>>(adj_row,adj_col,adj_val,inv,dense);
  k_loss<<<2048,256,0,stream>>>(sim,dense,loss_acc);
  k_loss_write<<<1,1,0,stream>>>(loss_acc,out_loss);

  // propagation
  k_spmm_u <<<NU,256,0,stream>>>(row_ptr,ebr,colsA,v_u,node_emb,usertok,u1);
  k_spmm_i1<<<NE,256,0,stream>>>(col_ptr,ebc,rowsA,v_i,alltok,usertok,node_emb,Att,i1);
  k_spmm_u <<<NU,256,0,stream>>>(row_ptr,ebr,colsA,v_u,i1,usertok,u2);
  k_spmm_i2<<<NE,256,0,stream>>>(col_ptr,ebc,rowsA,v_i,u1,Att,i1,node_emb,out_item);

  // prompt head
  k_sysfin<<<g642,256,0,stream>>>(sysid,alltok,u1,u2,sysf);
  k_q  <<<NBATCH,256,0,stream>>>(sysf,p1w1,p1b1,qbuf);
  k_p1 <<<g642,256,0,stream>>>(qbuf,p1w2,p1b2,sysf,p1buf);
  k_gemm<0,false,false><<<dim3(192,1),256,0,stream>>>(p1buf,p2w,p2b,nullptr,p2buf,NBATCH,P2N,H);
  k_perm<<<PROMPT_N/256,256,0,stream>>>(p2buf,out_prompt);
}

// Round 4
// 879.864 us; speedup vs baseline: 1.0866x; 1.0296x over previous
//
#include <hip/hip_runtime.h>

#define H     512
#define THD   768
#define MDIM  256
#define NE    16000
#define NU    2000
#define NI    4000
#define NNZ   40000
#define KTOP  10
#define NBATCH 64
#define NEDGE 60000          // NNZ + NU*KTOP
#define GAMA  0.1f
#define P2N   12288          // NL*NB*H
#define PROMPT_N 786432      // 24*64*512

__device__ __forceinline__ float sigmoidf(float x){ return 1.0f/(1.0f+expf(-x)); }

// ---------- small dense kernels (64 rows) ----------
__global__ void k_tok(const float* __restrict__ A, const float* __restrict__ W,
                      const float* __restrict__ bias, float* __restrict__ C){
  int b=blockIdx.x, c=blockIdx.y*256+threadIdx.x;
  const float* a=A+b*THD; float s=bias[c];
  for(int k=0;k<THD;k++) s+=a[k]*W[k*H+c];
  C[b*H+c]=s;
}

__global__ void k_gm(const int* __restrict__ sysid, const float* __restrict__ tok,
                     float* __restrict__ gm){
  int b=blockIdx.x, c=blockIdx.y*256+threadIdx.x;
  int sid=sysid[b]; float s=0.f, cnt=0.f;
  for(int j=0;j<NBATCH;j++){ if(sysid[j]==sid){ s+=tok[j*H+c]; cnt+=1.f; } }
  gm[b*H+c]=s/cnt;
}

// fused: filt = prelu(gm@trans_w+b)*gm ; hh = relu(filt@mw1+b1)   (one block per b)
__global__ __launch_bounds__(512) void k_filthh(const float* __restrict__ gm,
        const float* __restrict__ trans_w, const float* __restrict__ trans_b,
        const float* __restrict__ mw1, const float* __restrict__ mb1,
        const float* __restrict__ pa, float* __restrict__ hh){
  __shared__ float fl[512];
  __shared__ float hp[512];
  int b=blockIdx.x, t=threadIdx.x;
  const float* g=gm+b*H;
  float s=trans_b[t];
  for(int k=0;k<H;k++) s+=g[k]*trans_w[k*H+t];
  float al=pa[0]; float pr=(s>=0.f)? s : al*s;
  fl[t]=pr*g[t];
  __syncthreads();
  int m=t&255, half=t>>8;
  float s2=0.f; int k0=half*256;
  for(int k=0;k<256;k++) s2+=fl[k0+k]*mw1[(k0+k)*MDIM+m];
  hp[t]=s2;
  __syncthreads();
  if(t<256) hh[b*MDIM+t]=fmaxf(hp[t]+hp[t+256]+mb1[t],0.f);
}

// fused: uesel[b,c], ueT[c,b], enh = uesel @ mb2 (bias term)
__global__ void k_uprep(const int* __restrict__ sysid, const float* __restrict__ ue,
                        const float* __restrict__ mb2, float* __restrict__ uesel,
                        float* __restrict__ ueT, float* __restrict__ enh){
  int b=blockIdx.x, c=blockIdx.y*256+threadIdx.x;
  const float* u=ue+(size_t)sysid[b]*H;
  float v=u[c];
  uesel[b*H+c]=v;
  ueT[c*64+b]=v;
  float s=0.f;
  for(int h=0;h<H;h++) s+=u[h]*mb2[(size_t)h*H+c];
  enh[b*H+c]=s;
}

// ---------- big hypernet contraction ----------
// partials[m][b][k] = hh[b,m] * sum_h ueT[h,b]*W2[m,h*H+k]
#define HCH 32
__global__ __launch_bounds__(256) void k_big(const float* __restrict__ hh,
        const float* __restrict__ ueT, const float* __restrict__ w2,
        float* __restrict__ partials){
  __shared__ float a_lds[HCH][64];    // [h][b]
  __shared__ float w_lds[HCH][128];   // [h][k]
  int m=blockIdx.x;                   // 0..255
  int k0=blockIdx.y*128;              // 0,128,256,384
  int t=threadIdx.x;
  int tn=t&15, tm=t>>4;               // k-group (8 wide), b-group (4 wide)
  const float* w2m = w2 + (size_t)m*(size_t)(H*H);
  float4 ar0,ar1,wr0,wr1,wr2,wr3;
  ar0=*(const float4*)(ueT + (size_t)t*4);
  ar1=*(const float4*)(ueT + (size_t)(t+256)*4);
  {
    int i0=t, i1=t+256, i2=t+512, i3=t+768;
    wr0=*(const float4*)(w2m+(size_t)(i0>>5)*H+k0+(i0&31)*4);
    wr1=*(const float4*)(w2m+(size_t)(i1>>5)*H+k0+(i1&31)*4);
    wr2=*(const float4*)(w2m+(size_t)(i2>>5)*H+k0+(i2&31)*4);
    wr3=*(const float4*)(w2m+(size_t)(i3>>5)*H+k0+(i3&31)*4);
  }
  float acc[4][8]={};
  for(int hc=0;hc<16;hc++){
    __syncthreads();
    *(float4*)((float*)a_lds + t*4)      =ar0;
    *(float4*)((float*)a_lds + (t+256)*4)=ar1;
    *(float4*)((float*)w_lds + t*4)      =wr0;
    *(float4*)((float*)w_lds + (t+256)*4)=wr1;
    *(float4*)((float*)w_lds + (t+512)*4)=wr2;
    *(float4*)((float*)w_lds + (t+768)*4)=wr3;
    __syncthreads();
    if(hc<15){
      int h0=(hc+1)*HCH;
      ar0=*(const float4*)(ueT + (size_t)h0*64 + t*4);
      ar1=*(const float4*)(ueT + (size_t)h0*64 + (t+256)*4);
      int i0=t, i1=t+256, i2=t+512, i3=t+768;
      wr0=*(const float4*)(w2m+(size_t)(h0+(i0>>5))*H+k0+(i0&31)*4);
      wr1=*(const float4*)(w2m+(size_t)(h0+(i1>>5))*H+k0+(i1&31)*4);
      wr2=*(const float4*)(w2m+(size_t)(h0+(i2>>5))*H+k0+(i2&31)*4);
      wr3=*(const float4*)(w2m+(size_t)(h0+(i3>>5))*H+k0+(i3&31)*4);
    }
    #pragma unroll
    for(int hl=0;hl<HCH;hl++){
      float4 a4 =*(const float4*)&a_lds[hl][tm*4];
      float4 w4a=*(const float4*)&w_lds[hl][tn*8];
      float4 w4b=*(const float4*)&w_lds[hl][tn*8+4];
      acc[0][0]+=a4.x*w4a.x; acc[0][1]+=a4.x*w4a.y; acc[0][2]+=a4.x*w4a.z; acc[0][3]+=a4.x*w4a.w;
      acc[0][4]+=a4.x*w4b.x; acc[0][5]+=a4.x*w4b.y; acc[0][6]+=a4.x*w4b.z; acc[0][7]+=a4.x*w4b.w;
      acc[1][0]+=a4.y*w4a.x; acc[1][1]+=a4.y*w4a.y; acc[1][2]+=a4.y*w4a.z; acc[1][3]+=a4.y*w4a.w;
      acc[1][4]+=a4.y*w4b.x; acc[1][5]+=a4.y*w4b.y; acc[1][6]+=a4.y*w4b.z; acc[1][7]+=a4.y*w4b.w;
      acc[2][0]+=a4.z*w4a.x; acc[2][1]+=a4.z*w4a.y; acc[2][2]+=a4.z*w4a.z; acc[2][3]+=a4.z*w4a.w;
      acc[2][4]+=a4.z*w4b.x; acc[2][5]+=a4.z*w4b.y; acc[2][6]+=a4.z*w4b.z; acc[2][7]+=a4.z*w4b.w;
      acc[3][0]+=a4.w*w4a.x; acc[3][1]+=a4.w*w4a.y; acc[3][2]+=a4.w*w4a.z; acc[3][3]+=a4.w*w4a.w;
      acc[3][4]+=a4.w*w4b.x; acc[3][5]+=a4.w*w4b.y; acc[3][6]+=a4.w*w4b.z; acc[3][7]+=a4.w*w4b.w;
    }
  }
  #pragma unroll
  for(int bi=0;bi<4;bi++){
    int bb=tm*4+bi;
    float hv=hh[bb*MDIM+m];
    float* p=partials+((size_t)m*NBATCH+bb)*H+k0+tn*8;
    *(float4*)p    =make_float4(acc[bi][0]*hv,acc[bi][1]*hv,acc[bi][2]*hv,acc[bi][3]*hv);
    *(float4*)(p+4)=make_float4(acc[bi][4]*hv,acc[bi][5]*hv,acc[bi][6]*hv,acc[bi][7]*hv);
  }
}

__global__ void k_red1(const float* __restrict__ partials, float* __restrict__ partial2){
  int idx=blockIdx.x*256+threadIdx.x;      // 0..524287
  int g=idx>>15, col=idx&32767;
  const float* p=partials+(size_t)g*16*32768+col;
  float s=0.f;
  #pragma unroll
  for(int m=0;m<16;m++) s+=p[(size_t)m*32768];
  partial2[idx]=s;
}
// final reduce + scatter into alltok (pre-copied from user_emb)
__global__ void k_red2s(const int* __restrict__ sysid, const float* __restrict__ partial2,
                        const float* __restrict__ enh, float* __restrict__ alltok){
  int idx=blockIdx.x*256+threadIdx.x;      // 0..32767
  int b=idx>>9, k=idx&511;
  float s=enh[idx];
  #pragma unroll
  for(int g=0;g<16;g++) s+=partial2[(size_t)g*32768+idx];
  alltok[(size_t)sysid[b]*H+k]=s;          // duplicate sysids write identical values
}

__global__ void k_user_tok(const int* __restrict__ sysid, const float* __restrict__ gm,
                           const float* __restrict__ W, const float* __restrict__ bias,
                           const float* __restrict__ pa, float* __restrict__ usertok){
  int b=blockIdx.x, c=blockIdx.y*256+threadIdx.x;
  const float* a=gm+b*H; float s=bias[c];
  for(int k=0;k<H;k++) s+=a[k]*W[k*H+c];
  float al=pa[0]; float pr=(s>=0.f)? s : al*s;
  usertok[(size_t)sysid[b]*H+c]=pr*gm[b*H+c];
}

// ---------- tiled fp32 GEMM, BM=BN=64, BK=32 (small-matrix helper) ----------
template<int EPI, bool NT, bool AIDX>
__global__ __launch_bounds__(256) void k_gemm(const float* __restrict__ A,
        const float* __restrict__ Bm, const float* __restrict__ bias,
        const int* __restrict__ aidx, float* __restrict__ C, int M, int N, int K){
  __shared__ float As[32][68];
  __shared__ float Bs[32][68];
  int n0=blockIdx.x*64, m0=blockIdx.y*64;
  int t=threadIdx.x;
  int tn=t&15, tm=t>>4;
  float acc[4][4]={};
  for(int kt=0;kt<K;kt+=32){
    #pragma unroll
    for(int i=0;i<2;i++){
      int idx=t+i*256; int r=idx>>3, q=idx&7;
      int grow=m0+r;
      float4 v=make_float4(0.f,0.f,0.f,0.f);
      if(grow<M){
        const float* arow=A+(size_t)(AIDX? aidx[grow]:grow)*K;
        v=*(const float4*)(arow+kt+q*4);
      }
      As[q*4+0][r]=v.x; As[q*4+1][r]=v.y; As[q*4+2][r]=v.z; As[q*4+3][r]=v.w;
    }
    if(!NT){
      #pragma unroll
      for(int i=0;i<2;i++){
        int idx=t+i*256; int r=idx>>4, q=idx&15;
        float4 v=*(const float4*)(Bm+(size_t)(kt+r)*N+n0+q*4);
        *(float4*)&Bs[r][q*4]=v;
      }
    } else {
      #pragma unroll
      for(int i=0;i<2;i++){
        int idx=t+i*256; int r=idx>>3, q=idx&7;
        int gn=n0+r;
        float4 v=make_float4(0.f,0.f,0.f,0.f);
        if(gn<N) v=*(const float4*)(Bm+(size_t)gn*K+kt+q*4);
        Bs[q*4+0][r]=v.x; Bs[q*4+1][r]=v.y; Bs[q*4+2][r]=v.z; Bs[q*4+3][r]=v.w;
      }
    }
    __syncthreads();
    #pragma unroll 8
    for(int k=0;k<32;k++){
      float4 a4=*(const float4*)&As[k][tm*4];
      float4 b4=*(const float4*)&Bs[k][tn*4];
      acc[0][0]+=a4.x*b4.x; acc[0][1]+=a4.x*b4.y; acc[0][2]+=a4.x*b4.z; acc[0][3]+=a4.x*b4.w;
      acc[1][0]+=a4.y*b4.x; acc[1][1]+=a4.y*b4.y; acc[1][2]+=a4.y*b4.z; acc[1][3]+=a4.y*b4.w;
      acc[2][0]+=a4.z*b4.x; acc[2][1]+=a4.z*b4.y; acc[2][2]+=a4.z*b4.z; acc[2][3]+=a4.z*b4.w;
      acc[3][0]+=a4.w*b4.x; acc[3][1]+=a4.w*b4.y; acc[3][2]+=a4.w*b4.z; acc[3][3]+=a4.w*b4.w;
    }
    __syncthreads();
  }
  #pragma unroll
  for(int bi=0;bi<4;bi++){
    int row=m0+tm*4+bi; if(row>=M) continue;
    #pragma unroll
    for(int ki=0;ki<4;ki++){
      int col=n0+tn*4+ki; if(col>=N) continue;
      float v=acc[bi][ki];
      if(EPI==0){ if(bias) v+=bias[col]; }
      else { v=sigmoidf(v); }
      C[(size_t)row*N+col]=v;
    }
  }
}

// ---------- 128x128-tile sim GEMM, register-prefetch double buffered ----------
__global__ __launch_bounds__(512) void k_gemm_sim(const float* __restrict__ A,
        const float* __restrict__ Bm, float* __restrict__ C, int M, int N){
  __shared__ float As[32][132];
  __shared__ float Bs[32][132];
  int n0=blockIdx.x*128, m0=blockIdx.y*128;
  int t=threadIdx.x;
  int tn=t&31, tm=t>>5;
  float4 pa0,pa1,pb0,pb1;
  // prefetch kt=0
  {
    int i0=t, i1=t+512;
    int r0=i0>>3,q0=i0&7, r1=i1>>3,q1=i1&7;
    pa0=make_float4(0,0,0,0); pa1=make_float4(0,0,0,0);
    pb0=make_float4(0,0,0,0); pb1=make_float4(0,0,0,0);
    if(m0+r0<M) pa0=*(const float4*)(A+(size_t)(m0+r0)*H+q0*4);
    if(m0+r1<M) pa1=*(const float4*)(A+(size_t)(m0+r1)*H+q1*4);
    if(n0+r0<N) pb0=*(const float4*)(Bm+(size_t)(n0+r0)*H+q0*4);
    if(n0+r1<N) pb1=*(const float4*)(Bm+(size_t)(n0+r1)*H+q1*4);
  }
  float acc[8][4]={};
  for(int kt=0;kt<H;kt+=32){
    __syncthreads();
    {
      int i0=t, i1=t+512;
      int r0=i0>>3,q0=i0&7, r1=i1>>3,q1=i1&7;
      As[q0*4+0][r0]=pa0.x; As[q0*4+1][r0]=pa0.y; As[q0*4+2][r0]=pa0.z; As[q0*4+3][r0]=pa0.w;
      As[q1*4+0][r1]=pa1.x; As[q1*4+1][r1]=pa1.y; As[q1*4+2][r1]=pa1.z; As[q1*4+3][r1]=pa1.w;
      Bs[q0*4+0][r0]=pb0.x; Bs[q0*4+1][r0]=pb0.y; Bs[q0*4+2][r0]=pb0.z; Bs[q0*4+3][r0]=pb0.w;
      Bs[q1*4+0][r1]=pb1.x; Bs[q1*4+1][r1]=pb1.y; Bs[q1*4+2][r1]=pb1.z; Bs[q1*4+3][r1]=pb1.w;
    }
    __syncthreads();
    if(kt+32<H){
      int i0=t, i1=t+512;
      int r0=i0>>3,q0=i0&7, r1=i1>>3,q1=i1&7;
      pa0=make_float4(0,0,0,0); pa1=make_float4(0,0,0,0);
      pb0=make_float4(0,0,0,0); pb1=make_float4(0,0,0,0);
      if(m0+r0<M) pa0=*(const float4*)(A+(size_t)(m0+r0)*H+kt+32+q0*4);
      if(m0+r1<M) pa1=*(const float4*)(A+(size_t)(m0+r1)*H+kt+32+q1*4);
      if(n0+r0<N) pb0=*(const float4*)(Bm+(size_t)(n0+r0)*H+kt+32+q0*4);
      if(n0+r1<N) pb1=*(const float4*)(Bm+(size_t)(n0+r1)*H+kt+32+q1*4);
    }
    #pragma unroll 8
    for(int k=0;k<32;k++){
      float4 a0=*(const float4*)&As[k][tm*8];
      float4 a1=*(const float4*)&As[k][tm*8+4];
      float4 b0=*(const float4*)&Bs[k][tn*4];
      acc[0][0]+=a0.x*b0.x; acc[0][1]+=a0.x*b0.y; acc[0][2]+=a0.x*b0.z; acc[0][3]+=a0.x*b0.w;
      acc[1][0]+=a0.y*b0.x; acc[1][1]+=a0.y*b0.y; acc[1][2]+=a0.y*b0.z; acc[1][3]+=a0.y*b0.w;
      acc[2][0]+=a0.z*b0.x; acc[2][1]+=a0.z*b0.y; acc[2][2]+=a0.z*b0.z; acc[2][3]+=a0.z*b0.w;
      acc[3][0]+=a0.w*b0.x; acc[3][1]+=a0.w*b0.y; acc[3][2]+=a0.w*b0.z; acc[3][3]+=a0.w*b0.w;
      acc[4][0]+=a1.x*b0.x; acc[4][1]+=a1.x*b0.y; acc[4][2]+=a1.x*b0.z; acc[4][3]+=a1.x*b0.w;
      acc[5][0]+=a1.y*b0.x; acc[5][1]+=a1.y*b0.y; acc[5][2]+=a1.y*b0.z; acc[5][3]+=a1.y*b0.w;
      acc[6][0]+=a1.z*b0.x; acc[6][1]+=a1.z*b0.y; acc[6][2]+=a1.z*b0.z; acc[6][3]+=a1.z*b0.w;
      acc[7][0]+=a1.w*b0.x; acc[7][1]+=a1.w*b0.y; acc[7][2]+=a1.w*b0.z; acc[7][3]+=a1.w*b0.w;
    }
  }
  #pragma unroll
  for(int mi=0;mi<8;mi++){
    int row=m0+tm*8+mi; if(row>=M) continue;
    #pragma unroll
    for(int nj=0;nj<4;nj++){
      int col=n0+tn*4+nj; if(col>=N) continue;
      C[(size_t)row*N+col]=sigmoidf(acc[mi][nj]);
    }
  }
}

__global__ __launch_bounds__(256) void k_rownorm(float* __restrict__ X){
  int r=blockIdx.x, t=threadIdx.x;
  float v1=X[(size_t)r*H+t], v2=X[(size_t)r*H+t+256];
  float ss=v1*v1+v2*v2;
  for(int o=32;o;o>>=1) ss+=__shfl_xor(ss,o);
  __shared__ float red[4];
  if((t&63)==0) red[t>>6]=ss;
  __syncthreads();
  float tot=red[0]+red[1]+red[2]+red[3];
  float nrm=fmaxf(sqrtf(tot),1e-12f);
  X[(size_t)r*H+t]=v1/nrm; X[(size_t)r*H+t+256]=v2/nrm;
}

// ---------- top-k (lax.top_k semantics), wave-shuffle reduction ----------
__global__ __launch_bounds__(256) void k_topk(const float* __restrict__ sim,
        float* __restrict__ tv, int* __restrict__ ti){
  __shared__ float vals[NI];
  __shared__ float rv[4];
  __shared__ int   ri[4];
  int u=blockIdx.x, t=threadIdx.x;
  for(int i=t;i<NI;i+=256) vals[i]=sim[(size_t)u*NI+i];
  __syncthreads();
  for(int k=0;k<KTOP;k++){
    float bv=-1e30f; int bi=NI;
    for(int i=t;i<NI;i+=256){
      float v=vals[i];
      if(v>bv || (v==bv && i<bi)){ bv=v; bi=i; }
    }
    #pragma unroll
    for(int o=32;o;o>>=1){
      float ov=__shfl_xor(bv,o); int oi=__shfl_xor(bi,o);
      if(ov>bv || (ov==bv && oi<bi)){ bv=ov; bi=oi; }
    }
    if((t&63)==0){ rv[t>>6]=bv; ri[t>>6]=bi; }
    __syncthreads();
    float fv=rv[0]; int fi=ri[0];
    #pragma unroll
    for(int w=1;w<4;w++){
      float ov=rv[w]; int oi=ri[w];
      if(ov>fv || (ov==fv && oi<fi)){ fv=ov; fi=oi; }
    }
    if(t==0){ tv[u*KTOP+k]=fv; ti[u*KTOP+k]=fi; vals[fi]=-1e30f; }
    __syncthreads();
  }
}

// ---------- edges, CSR, normalizers ----------
__global__ void k_edges(const int* __restrict__ adj_row, const int* __restrict__ adj_col,
        const float* __restrict__ adj_val, const int* __restrict__ itemid,
        const float* __restrict__ tv, const int* __restrict__ ti,
        int* __restrict__ rows, int* __restrict__ cols, float* __restrict__ vals,
        float* __restrict__ seg_r, float* __restrict__ seg_c,
        int* __restrict__ row_cnt, int* __restrict__ col_cnt, int* __restrict__ inv){
  int e=blockIdx.x*256+threadIdx.x; if(e>=NEDGE) return;
  if(e<NI) inv[itemid[e]]=e;                 // inv scatter (memset -1 done earlier)
  int r,c; float v;
  if(e<NNZ){ r=adj_row[e]; c=adj_col[e]; v=adj_val[e]; }
  else { int x=e-NNZ; int u=x/KTOP; r=u; c=itemid[ti[x]]; v=tv[x]; }
  rows[e]=r; cols[e]=c; vals[e]=v;
  atomicAdd(&seg_r[r],v); atomicAdd(&seg_c[c],v);
  atomicAdd(&row_cnt[r],1); atomicAdd(&col_cnt[c],1);
}

__global__ __launch_bounds__(1024) void k_scan(const int* __restrict__ rc, int* __restrict__ rp,
        const int* __restrict__ cc, int* __restrict__ cp){
  const int* cnt; int* ptr; int n;
  if(blockIdx.x==0){ cnt=rc; ptr=rp; n=NU; } else { cnt=cc; ptr=cp; n=NE; }
  int t=threadIdx.x;
  int chunk=(n+1023)>>10;
  int base=t*chunk;
  int s=0;
  for(int i=0;i<chunk;i++){ int j=base+i; if(j<n) s+=cnt[j]; }
  __shared__ int buf[1024];
  buf[t]=s; __syncthreads();
  for(int off=1;off<1024;off<<=1){
    int y=(t>=off)? buf[t-off]:0;
    __syncthreads();
    buf[t]+=y;
    __syncthreads();
  }
  int run=buf[t]-s;
  for(int i=0;i<chunk;i++){ int j=base+i; if(j<n){ ptr[j]=run; run+=cnt[j]; } }
  if(t==1023) ptr[n]=buf[1023];
}

// fused: CSR fill + v_u/v_i + dense scatter
__global__ void k_fill(const int* __restrict__ rows, const int* __restrict__ cols,
        const float* __restrict__ vals,
        const int* __restrict__ row_ptr, const int* __restrict__ col_ptr,
        const float* __restrict__ seg_r, const float* __restrict__ seg_c,
        int* __restrict__ fr, int* __restrict__ fc,
        int* __restrict__ ebr, int* __restrict__ ebc,
        float* __restrict__ v_u, float* __restrict__ v_i,
        const int* __restrict__ inv, float* __restrict__ dense){
  int e=blockIdx.x*256+threadIdx.x; if(e>=NEDGE) return;
  int r=rows[e], c=cols[e];
  ebr[row_ptr[r]+atomicAdd(&fr[r],1)]=e;
  ebc[col_ptr[c]+atomicAdd(&fc[c],1)]=e;
  v_u[e]=vals[e]/seg_r[r];
  v_i[e]=vals[e]/seg_c[c];
  if(e<NNZ){
    int ic=inv[c];
    if(ic>=0) atomicAdd(&dense[(size_t)r*NI+ic],vals[e]);
  }
}

// ---------- SpMM kernels (CSR, deterministic per-row loop) ----------
__global__ __launch_bounds__(256) void k_spmm_u(const int* __restrict__ row_ptr,
        const int* __restrict__ ebr, const int* __restrict__ cols,
        const float* __restrict__ v_u, const float* __restrict__ X,
        const float* __restrict__ usertok, float* __restrict__ out){
  int u=blockIdx.x, t=threadIdx.x;
  float a0=0.f,a1=0.f;
  int s=row_ptr[u], e1=row_ptr[u+1];
  for(int j=s;j<e1;j++){
    int e=ebr[j]; float v=v_u[e];
    const float* xr=X+(size_t)cols[e]*H;
    a0+=v*xr[t]; a1+=v*xr[t+256];
  }
  float u0=usertok[(size_t)u*H+t], u1v=usertok[(size_t)u*H+t+256];
  out[(size_t)u*H+t]=a0+a0*u0; out[(size_t)u*H+t+256]=a1+a1*u1v;
}

__global__ __launch_bounds__(256) void k_spmm_i1(const int* __restrict__ col_ptr,
        const int* __restrict__ ebc, const int* __restrict__ rows,
        const float* __restrict__ v_i, const float* __restrict__ alltok,
        const float* __restrict__ usertok, const float* __restrict__ i0,
        float* __restrict__ Att, float* __restrict__ i1){
  int i=blockIdx.x, t=threadIdx.x;
  float aA0=0.f,aA1=0.f,aU0=0.f,aU1=0.f;
  int s=col_ptr[i], e1=col_ptr[i+1];
  for(int j=s;j<e1;j++){
    int e=ebc[j]; float v=v_i[e]; int r=rows[e];
    const float* ur=usertok+(size_t)r*H;
    const float* ar=alltok+(size_t)r*H;
    aA0+=v*ur[t]; aA1+=v*ur[t+256];
    aU0+=v*ar[t]; aU1+=v*ar[t+256];
  }
  size_t o=(size_t)i*H;
  Att[o+t]=aA0; Att[o+t+256]=aA1;
  i1[o+t]=aU0+aA0*i0[o+t]; i1[o+t+256]=aU1+aA1*i0[o+t+256];
}

__global__ __launch_bounds__(256) void k_spmm_i2(const int* __restrict__ col_ptr,
        const int* __restrict__ ebc, const int* __restrict__ rows,
        const float* __restrict__ v_i, const float* __restrict__ u1,
        const float* __restrict__ Att, const float* __restrict__ i1,
        const float* __restrict__ i0, float* __restrict__ item_out){
  int i=blockIdx.x, t=threadIdx.x;
  float a0=0.f,a1=0.f;
  int s=col_ptr[i], e1=col_ptr[i+1];
  for(int j=s;j<e1;j++){
    int e=ebc[j]; float v=v_i[e];
    const float* ur=u1+(size_t)rows[e]*H;
    a0+=v*ur[t]; a1+=v*ur[t+256];
  }
  size_t o=(size_t)i*H;
  float i2a=a0+Att[o+t]*i1[o+t];
  float i2b=a1+Att[o+t+256]*i1[o+t+256];
  item_out[o+t]=(i0[o+t]+i1[o+t]+i2a)/3.0f;
  item_out[o+t+256]=(i0[o+t+256]+i1[o+t+256]+i2b)/3.0f;
}

// ---------- loss ----------
__global__ __launch_bounds__(256) void k_loss(const float* __restrict__ sim,
        const float* __restrict__ dense, float* __restrict__ acc){
  size_t n4=(size_t)NU*NI/4;
  float s=0.f;
  for(size_t i=(size_t)blockIdx.x*256+threadIdx.x; i<n4; i+=(size_t)gridDim.x*256){
    float4 a=((const float4*)sim)[i], d=((const float4*)dense)[i];
    float dx=a.x-d.x, dy=a.y-d.y, dz=a.z-d.z, dw=a.w-d.w;
    s+=dx*dx+dy*dy+dz*dz+dw*dw;
  }
  __shared__ float red[256];
  red[threadIdx.x]=s; __syncthreads();
  for(int o=128;o;o>>=1){ if(threadIdx.x<o) red[threadIdx.x]+=red[threadIdx.x+o]; __syncthreads(); }
  if(threadIdx.x==0) atomicAdd(acc,red[0]);
}
__global__ void k_loss_write(const float* __restrict__ acc, float* __restrict__ out){
  out[0]=GAMA*(acc[0]/(float)((size_t)NU*NI));
}

// ---------- prompt head: fused sysfin + q + p1 (one block per b) ----------
__global__ __launch_bounds__(512) void k_sysq_p1(const int* __restrict__ sysid,
        const float* __restrict__ u0, const float* __restrict__ u1, const float* __restrict__ u2,
        const float* __restrict__ p1w1, const float* __restrict__ p1b1,
        const float* __restrict__ p1w2, const float* __restrict__ p1b2,
        float* __restrict__ p1buf){
  __shared__ float sf[512];
  __shared__ float hp[512];
  __shared__ float qv[256];
  int b=blockIdx.x, t=threadIdx.x;
  size_t o=(size_t)sysid[b]*H+t;
  float sfv=(u0[o]+u1[o]+u2[o])/3.0f;
  sf[t]=sfv;
  __syncthreads();
  int m=t&255, half=t>>8;
  float s=0.f; int k0=half*256;
  for(int k=0;k<256;k++) s+=sf[k0+k]*p1w1[(k0+k)*MDIM+m];
  hp[t]=s;
  __syncthreads();
  if(t<256) qv[t]=fmaxf(hp[t]+hp[t+256]+p1b1[t],0.f);
  __syncthreads();
  float s2=p1b2[t];
  for(int k=0;k<256;k++) s2+=qv[k]*p1w2[k*H+t];
  p1buf[b*H+t]=s2+sf[t];
}

__global__ void k_perm(const float* __restrict__ p2, float* __restrict__ out){
  int idx=blockIdx.x*256+threadIdx.x;       // 0..786431
  int x=idx&511;
  int b=(idx>>9)&63;
  int c=idx>>15;                            // 0..23
  out[idx]=p2[(size_t)b*P2N+c*512+x];
}

// ---------- host ----------
extern "C" void kernel_launch(void* const* d_in, const int* in_sizes, int n_in,
                              void* d_out, int out_size, void* d_ws, size_t ws_size,
                              hipStream_t stream){
  const int*   sysid   =(const int*)  d_in[0];
  const int*   adj_row =(const int*)  d_in[1];
  const int*   adj_col =(const int*)  d_in[2];
  const int*   itemid  =(const int*)  d_in[3];
  const float* tok_emb =(const float*)d_in[4];
  const float* adj_val =(const float*)d_in[5];
  const float* node_emb=(const float*)d_in[6];
  const float* user_emb=(const float*)d_in[7];
  const float* tp_w    =(const float*)d_in[8];
  const float* tp_b    =(const float*)d_in[9];
  const float* trans_w =(const float*)d_in[10];
  const float* trans_b =(const float*)d_in[11];
  const float* trt_w   =(const float*)d_in[12];
  const float* trt_b   =(const float*)d_in[13];
  const float* mw1     =(const float*)d_in[14];
  const float* mb1     =(const float*)d_in[15];
  const float* mw2     =(const float*)d_in[16];
  const float* mb2     =(const float*)d_in[17];
  const float* sw1     =(const float*)d_in[18];
  const float* sw2     =(const float*)d_in[19];
  const float* p1w1    =(const float*)d_in[20];
  const float* p1b1    =(const float*)d_in[21];
  const float* p1w2    =(const float*)d_in[22];
  const float* p1b2    =(const float*)d_in[23];
  const float* p2w     =(const float*)d_in[24];
  const float* p2b     =(const float*)d_in[25];
  const float* pa      =(const float*)d_in[26];

  float* out_prompt=(float*)d_out;
  float* out_item  =out_prompt+PROMPT_N;
  float* out_loss  =out_item+(size_t)NE*H;

  // workspace arena
  char* ws=(char*)d_ws; size_t off=0;
  auto A=[&](size_t bytes)->char*{ char* p=ws+off; off+=(bytes+255)&~(size_t)255; return p; };
  float* tok     =(float*)A((size_t)NBATCH*H*4);
  float* gm      =(float*)A((size_t)NBATCH*H*4);
  float* hh      =(float*)A((size_t)NBATCH*MDIM*4);
  float* uesel   =(float*)A((size_t)NBATCH*H*4);
  float* ueT     =(float*)A((size_t)H*NBATCH*4);
  float* enh     =(float*)A((size_t)NBATCH*H*4);
  float* irep    =(float*)A((size_t)NI*H*4);             // 8 MB
  float* alltok  =(float*)A((size_t)NU*H*4);
  float* urep    =(float*)A((size_t)NU*H*4);
  float* u1      =(float*)A((size_t)NU*H*4);
  float* u2      =(float*)A((size_t)NU*H*4);
  float* big     =(float*)A((size_t)16384000*4);         // 64 MB region, time-shared:
  float* partials=big;                                   //  phase A: 256*64*512 f (32 MB)
  float* partial2=big+8388608;                           //  phase A: 16*32768 f (2 MB)
  float* sim     =big;                                   //  phase B: 8,000,000 f
  float* dense   =big+8000000;                           //  phase B: 8,000,000 f
  float* Att     =big;                                   //  phase C: 8,192,000 f
  float* i1      =big+8192000;                           //  phase C: 8,192,000 f
  float* tv      =(float*)A((size_t)NU*KTOP*4);
  int*   ti      =(int*)  A((size_t)NU*KTOP*4);
  int*   rowsA   =(int*)  A((size_t)NEDGE*4);
  int*   colsA   =(int*)  A((size_t)NEDGE*4);
  float* valsA   =(float*)A((size_t)NEDGE*4);
  float* v_u     =(float*)A((size_t)NEDGE*4);
  float* v_i     =(float*)A((size_t)NEDGE*4);
  int*   ebr     =(int*)  A((size_t)NEDGE*4);
  int*   ebc     =(int*)  A((size_t)NEDGE*4);
  int*   row_ptr =(int*)  A((size_t)(NU+1)*4);
  int*   col_ptr =(int*)  A((size_t)(NE+1)*4);
  // contiguous zero block: usertok + seg/cnt/fill counters + loss acc
  size_t zb_bytes=(size_t)NU*H*4 + (size_t)(NU+NE)*4*3 + 256;
  char*  zb      =A(zb_bytes);
  float* usertok =(float*)zb;
  float* seg_r   =usertok+(size_t)NU*H;
  float* seg_c   =seg_r+NU;
  int*   row_cnt =(int*)(seg_c+NE);
  int*   col_cnt =row_cnt+NU;
  int*   fr      =col_cnt+NE;
  int*   fc      =fr+NU;
  float* loss_acc=(float*)(fc+NE);
  int*   inv     =(int*)  A((size_t)NE*4);
  float* p1buf   =(float*)A((size_t)NBATCH*H*4);
  float* p2buf   =(float*)A((size_t)NBATCH*P2N*4);
  (void)ws_size; (void)n_in; (void)in_sizes; (void)out_size;

  dim3 g642(NBATCH,2);

  // independent init first (overlap-friendly at graph level)
  hipMemcpyAsync(alltok,user_emb,(size_t)NU*H*4,hipMemcpyDeviceToDevice,stream);
  hipMemsetAsync(zb,0,zb_bytes,stream);
  hipMemsetAsync(inv,0xFF,(size_t)NE*4,stream);
  hipMemsetAsync(dense,0,(size_t)8000000*4,stream);

  // dense front-end
  k_tok   <<<g642,256,0,stream>>>(tok_emb,tp_w,tp_b,tok);
  k_gm    <<<g642,256,0,stream>>>(sysid,tok,gm);
  k_filthh<<<NBATCH,512,0,stream>>>(gm,trans_w,trans_b,mw1,mb1,pa,hh);
  k_uprep <<<g642,256,0,stream>>>(sysid,user_emb,mb2,uesel,ueT,enh);
  k_big   <<<dim3(256,4),256,0,stream>>>(hh,ueT,mw2,partials);
  k_red1  <<<2048,256,0,stream>>>(partials,partial2);
  k_red2s <<<128,256,0,stream>>>(sysid,partial2,enh,alltok);
  k_user_tok<<<g642,256,0,stream>>>(sysid,gm,trt_w,trt_b,pa,usertok);

  // similarity
  k_gemm<0,false,false><<<dim3(8,32),256,0,stream>>>(alltok,sw1,nullptr,nullptr,urep,NU,H,H);
  k_gemm<0,false,true> <<<dim3(8,63),256,0,stream>>>(node_emb,sw2,nullptr,itemid,irep,NI,H,H);
  k_rownorm<<<NU,256,0,stream>>>(urep);
  k_rownorm<<<NI,256,0,stream>>>(irep);
  k_gemm_sim<<<dim3(32,16),512,0,stream>>>(urep,irep,sim,NU,NI);
  k_topk<<<NU,256,0,stream>>>(sim,tv,ti);

  // edges + CSR (+inv scatter, +vuvi, +dense scatter)
  k_edges<<<(NEDGE+255)/256,256,0,stream>>>(adj_row,adj_col,adj_val,itemid,tv,ti,
                                            rowsA,colsA,valsA,seg_r,seg_c,row_cnt,col_cnt,inv);
  k_scan<<<2,1024,0,stream>>>(row_cnt,row_ptr,col_cnt,col_ptr);
  k_fill<<<(NEDGE+255)/256,256,0,stream>>>(rowsA,colsA,valsA,row_ptr,col_ptr,seg_r,seg_c,
                                           fr,fc,ebr,ebc,v_u,v_i,inv,dense);

  // loss (consumes sim+dense, must finish before Att/i1 reuse the region)
  k_loss<<<2048,256,0,stream>>>(sim,dense,loss_acc);
  k_loss_write<<<1,1,0,stream>>>(loss_acc,out_loss);

  // propagation
  k_spmm_u <<<NU,256,0,stream>>>(row_ptr,ebr,colsA,v_u,node_emb,usertok,u1);
  k_spmm_i1<<<NE,256,0,stream>>>(col_ptr,ebc,rowsA,v_i,alltok,usertok,node_emb,Att,i1);
  k_spmm_u <<<NU,256,0,stream>>>(row_ptr,ebr,colsA,v_u,i1,usertok,u2);
  k_spmm_i2<<<NE,256,0,stream>>>(col_ptr,ebc,rowsA,v_i,u1,Att,i1,node_emb,out_item);

  // prompt head
  k_sysq_p1<<<NBATCH,512,0,stream>>>(sysid,alltok,u1,u2,p1w1,p1b1,p1w2,p1b2,p1buf);
  k_gemm<0,false,false><<<dim3(192,1),256,0,stream>>>(p1buf,p2w,p2b,nullptr,p2buf,NBATCH,P2N,H);
  k_perm<<<PROMPT_N/256,256,0,stream>>>(p2buf,out_prompt);
}